// Round 6
// baseline (643.594 us; speedup 1.0000x reference)
//
#include <hip/hip_runtime.h>

#define NODES_CH 128   // IN_CH == HID == 128
#define OUTW 64

// ---------------- CSR build ----------------

__global__ void k_zero(int* __restrict__ p, int n) {
    int i = blockIdx.x * blockDim.x + threadIdx.x;
    if (i < n) p[i] = 0;
}

__global__ void k_degree(const int* __restrict__ dstI, int* __restrict__ deg, int E) {
    int e = blockIdx.x * blockDim.x + threadIdx.x;
    if (e < E) atomicAdd(&deg[dstI[e]], 1);
}

// single-block exclusive scan; also inits cursor
__global__ __launch_bounds__(1024)
void k_scan(const int* __restrict__ deg, int* __restrict__ rp,
            int* __restrict__ cursor, int n) {
    __shared__ int wsum[16];
    int tid  = threadIdx.x;
    int lane = tid & 63;
    int wid  = tid >> 6;
    int carry = 0;
    for (int base = 0; base < n; base += 1024) {
        int i = base + tid;
        int v = (i < n) ? deg[i] : 0;
        int x = v;
        #pragma unroll
        for (int off = 1; off < 64; off <<= 1) {
            int t = __shfl_up(x, off, 64);
            if (lane >= off) x += t;
        }
        if (lane == 63) wsum[wid] = x;
        __syncthreads();
        if (wid == 0) {
            int y = (lane < 16) ? wsum[lane] : 0;
            #pragma unroll
            for (int off = 1; off < 16; off <<= 1) {
                int t = __shfl_up(y, off, 64);
                if (lane >= off) y += t;
            }
            if (lane < 16) wsum[lane] = y;
        }
        __syncthreads();
        int woff  = (wid > 0) ? wsum[wid - 1] : 0;
        int incl  = x + woff;
        int total = wsum[15];
        if (i < n) {
            int ex = carry + incl - v;
            rp[i] = ex;
            cursor[i] = ex;
        }
        carry += total;
        __syncthreads();  // protect wsum before next chunk overwrites
    }
    if (tid == 0) rp[n] = carry;
}

__global__ void k_fill(const int* __restrict__ srcI, const int* __restrict__ dstI,
                       int* __restrict__ cursor, int* __restrict__ colA, int E) {
    int e = blockIdx.x * blockDim.x + threadIdx.x;
    if (e < E) {
        int d = dstI[e];
        int p = atomicAdd(&cursor[d], 1);
        colA[p] = srcI[e];
    }
}

// ---------------- repack row-major [N][128] -> seg-major [8][N][16] ----------------
__global__ void k_repack(const float* __restrict__ X, float* __restrict__ XS, int n) {
    int i = blockIdx.x * blockDim.x + threadIdx.x;
    if (i >= n * 32) return;
    int node = i >> 5, c4 = i & 31;
    float4 v = ((const float4*)X)[i];
    ((float4*)XS)[(size_t)(c4 >> 2) * n * 4 + (size_t)node * 4 + (c4 & 3)] = v;
}

// ---------------- segmented mean aggregation ----------------
// grid (ceil(n/4), 8): segment = blockIdx.y (slow dim -> whole chip works one
// 3.2 MB column slice at a time; fits every XCD L2 with full 128B lines).
// Wave per node-segment: 8 edge slots x 8 float2 channels (16 floats/seg).
__global__ __launch_bounds__(256)
void k_agg_seg(const float* __restrict__ XS, const int* __restrict__ rp,
               const int* __restrict__ colA, float* __restrict__ out, int n) {
    int node = (blockIdx.x << 2) + (threadIdx.x >> 6);
    if (node >= n) return;
    int lane = threadIdx.x & 63;
    int es = lane >> 3;      // 8 edge slots
    int ch = lane & 7;       // 8 float2 channels
    int seg = blockIdx.y;
    int beg = rp[node], end = rp[node + 1];
    const float2* __restrict__ XS2 = (const float2*)XS;  // [8][n][8]
    size_t segbase = (size_t)seg * n * 8;
    float2 s = make_float2(0.f, 0.f);
    for (int e = beg + es; e < end; e += 8) {
        int c = colA[e];
        float2 v = XS2[segbase + (size_t)c * 8 + ch];
        s.x += v.x; s.y += v.y;
    }
    s.x += __shfl_xor(s.x, 8);  s.y += __shfl_xor(s.y, 8);
    s.x += __shfl_xor(s.x, 16); s.y += __shfl_xor(s.y, 16);
    s.x += __shfl_xor(s.x, 32); s.y += __shfl_xor(s.y, 32);
    if (es == 0) {
        float inv = 1.f / (float)((end > beg) ? (end - beg) : 1);
        ((float2*)out)[(size_t)node * 64 + seg * 8 + ch] =
            make_float2(s.x * inv, s.y * inv);
    }
}

// ---------------- fallback row-major aggregation (proven R5 path) ----------------
__global__ __launch_bounds__(256)
void k_agg_row(const float* __restrict__ X, const int* __restrict__ rp,
               const int* __restrict__ colA, float* __restrict__ out, int n) {
    int node = (blockIdx.x << 2) + (threadIdx.x >> 6);
    if (node >= n) return;
    int lane = threadIdx.x & 63;
    int eh = lane >> 5;
    int c4 = lane & 31;
    int beg = rp[node], end = rp[node + 1];
    const float4* __restrict__ X4 = (const float4*)X;
    float4 s = make_float4(0.f, 0.f, 0.f, 0.f);
    int e = beg + eh;
    for (; e + 2 < end; e += 4) {
        int c0 = colA[e];
        int c1 = colA[e + 2];
        float4 v0 = X4[(size_t)c0 * 32 + c4];
        float4 v1 = X4[(size_t)c1 * 32 + c4];
        s.x += v0.x + v1.x; s.y += v0.y + v1.y;
        s.z += v0.z + v1.z; s.w += v0.w + v1.w;
    }
    if (e < end) {
        int c0 = colA[e];
        float4 v0 = X4[(size_t)c0 * 32 + c4];
        s.x += v0.x; s.y += v0.y; s.z += v0.z; s.w += v0.w;
    }
    s.x += __shfl_xor(s.x, 32);
    s.y += __shfl_xor(s.y, 32);
    s.z += __shfl_xor(s.z, 32);
    s.w += __shfl_xor(s.w, 32);
    if (eh == 0) {
        float inv = 1.f / (float)((end > beg) ? (end - beg) : 1);
        ((float4*)out)[(size_t)node * 32 + c4] =
            make_float4(s.x * inv, s.y * inv, s.z * inv, s.w * inv);
    }
}

// ---------------- fused SAGE linear ----------------
// R5-proven inner structure (72 VGPR, zero conflicts, no scratch), re-tiled
// for occupancy: 32 rows/block, K-chunk 32 (16 KiB LDS), acc[2][8] ->
// grid ceil(N/32)=1563 blocks, 8 blocks/CU resident (thread-cap), one tranche.
// MODE 0 (+relu, 128 cols, stride 128): SEGOUT=1 also writes seg-major copy.
// MODE 1: [Wmu|Wls] virtual 128 cols -> split 64-col outputs.
// k-loop pragma'd "unroll 2" ONLY (R2/R4 scratch-blowup lesson).
template <int MODE, int SEGOUT>
__global__ __launch_bounds__(256, 2)
void k_gemm(const float* __restrict__ A0, const float* __restrict__ A1,
            const float* __restrict__ Wa0, const float* __restrict__ Wb0,
            const float* __restrict__ Wa1, const float* __restrict__ Wb1,
            const float* __restrict__ ba, const float* __restrict__ bb,
            float* __restrict__ out0, float* __restrict__ out1,
            float* __restrict__ outseg, int N) {
    __shared__ float Wlds[32 * 128];  // 16 KiB: one 32-k chunk x 128 cols
    const int tid = threadIdx.x;
    const int cg  = tid & 15;
    const int rg  = tid >> 4;
    const int rbase = blockIdx.x * 32 + rg * 2;

    float acc[2][8];
    #pragma unroll
    for (int r = 0; r < 2; r++)
        #pragma unroll
        for (int c = 0; c < 8; c++) acc[r][c] = 0.f;

    for (int phase = 0; phase < 2; ++phase) {
        const float* __restrict__ A = phase ? A1 : A0;
        for (int kc = 0; kc < 4; ++kc) {
            __syncthreads();
            if (MODE == 0) {
                const float* __restrict__ W = phase ? Wa1 : Wa0;  // [128][128]
                for (int i = tid; i < 1024; i += 256) {
                    int kr = i >> 5, c4 = i & 31;
                    ((float4*)Wlds)[i] =
                        *(const float4*)(W + (size_t)(kc * 32 + kr) * 128 + c4 * 4);
                }
            } else {
                const float* __restrict__ WA = phase ? Wa1 : Wa0;  // [128][64] mu
                const float* __restrict__ WB = phase ? Wb1 : Wb0;  // [128][64] ls
                for (int i = tid; i < 1024; i += 256) {
                    int kr = i >> 5, c4 = i & 31;
                    const float* s = (c4 < 16)
                        ? (WA + (size_t)(kc * 32 + kr) * 64 + c4 * 4)
                        : (WB + (size_t)(kc * 32 + kr) * 64 + (c4 - 16) * 4);
                    ((float4*)Wlds)[i] = *(const float4*)s;
                }
            }
            __syncthreads();
            #pragma unroll 2
            for (int k = 0; k < 32; k += 4) {
                float4 a[2];
                #pragma unroll
                for (int r = 0; r < 2; r++) {
                    int row = rbase + r;
                    a[r] = (row < N)
                        ? *(const float4*)(A + (size_t)row * 128 + kc * 32 + k)
                        : make_float4(0.f, 0.f, 0.f, 0.f);
                }
                #pragma unroll
                for (int kk = 0; kk < 4; kk++) {
                    float4 w0 = *(const float4*)(Wlds + (k + kk) * 128 + cg * 4);
                    float4 w1 = *(const float4*)(Wlds + (k + kk) * 128 + 64 + cg * 4);
                    #pragma unroll
                    for (int r = 0; r < 2; r++) {
                        float av = (kk == 0) ? a[r].x : (kk == 1) ? a[r].y
                                 : (kk == 2) ? a[r].z : a[r].w;
                        acc[r][0] += av * w0.x;
                        acc[r][1] += av * w0.y;
                        acc[r][2] += av * w0.z;
                        acc[r][3] += av * w0.w;
                        acc[r][4] += av * w1.x;
                        acc[r][5] += av * w1.y;
                        acc[r][6] += av * w1.z;
                        acc[r][7] += av * w1.w;
                    }
                }
            }
        }
    }

    // epilogue
    if (MODE == 0) {
        const float4 bv0 = *(const float4*)(ba + cg * 4);
        const float4 bv1 = *(const float4*)(ba + 64 + cg * 4);
        #pragma unroll
        for (int r = 0; r < 2; r++) {
            int row = rbase + r;
            if (row >= N) continue;
            float4 v0, v1;
            v0.x = fmaxf(acc[r][0] + bv0.x, 0.f);
            v0.y = fmaxf(acc[r][1] + bv0.y, 0.f);
            v0.z = fmaxf(acc[r][2] + bv0.z, 0.f);
            v0.w = fmaxf(acc[r][3] + bv0.w, 0.f);
            v1.x = fmaxf(acc[r][4] + bv1.x, 0.f);
            v1.y = fmaxf(acc[r][5] + bv1.y, 0.f);
            v1.z = fmaxf(acc[r][6] + bv1.z, 0.f);
            v1.w = fmaxf(acc[r][7] + bv1.w, 0.f);
            *(float4*)(out0 + (size_t)row * 128 + cg * 4) = v0;
            *(float4*)(out0 + (size_t)row * 128 + 64 + cg * 4) = v1;
            if (SEGOUT) {
                // seg-major copy [8][N][16]: cols cg*4 -> seg cg>>2; +64 -> +4
                *(float4*)(outseg + (size_t)(cg >> 2) * N * 16
                           + (size_t)row * 16 + (cg & 3) * 4) = v0;
                *(float4*)(outseg + (size_t)(4 + (cg >> 2)) * N * 16
                           + (size_t)row * 16 + (cg & 3) * 4) = v1;
            }
        }
    } else {
        const float4 bm = *(const float4*)(ba + cg * 4);
        const float4 bl = *(const float4*)(bb + cg * 4);
        #pragma unroll
        for (int r = 0; r < 2; r++) {
            int row = rbase + r;
            if (row >= N) continue;
            float4 vm, vl;
            vm.x = acc[r][0] + bm.x; vm.y = acc[r][1] + bm.y;
            vm.z = acc[r][2] + bm.z; vm.w = acc[r][3] + bm.w;
            vl.x = acc[r][4] + bl.x; vl.y = acc[r][5] + bl.y;
            vl.z = acc[r][6] + bl.z; vl.w = acc[r][7] + bl.w;
            *(float4*)(out0 + (size_t)row * 64 + cg * 4) = vm;
            *(float4*)(out1 + (size_t)row * 64 + cg * 4) = vl;
        }
    }
}

// ---------------- launch ----------------

extern "C" void kernel_launch(void* const* d_in, const int* in_sizes, int n_in,
                              void* d_out, int out_size, void* d_ws, size_t ws_size,
                              hipStream_t stream) {
    const float* x     = (const float*)d_in[0];
    const int*   ei    = (const int*)d_in[1];
    const float* W1_l  = (const float*)d_in[2];
    const float* b1    = (const float*)d_in[3];
    const float* W1_r  = (const float*)d_in[4];
    const float* Wmu_l = (const float*)d_in[5];
    const float* bmu   = (const float*)d_in[6];
    const float* Wmu_r = (const float*)d_in[7];
    const float* Wls_l = (const float*)d_in[8];
    const float* bls   = (const float*)d_in[9];
    const float* Wls_r = (const float*)d_in[10];

    const int N = in_sizes[0] / NODES_CH;  // 50000
    const int E = in_sizes[1] / 2;         // 800000
    const int* srcI = ei;
    const int* dstI = ei + E;

    const int NP = (N + 63) & ~63;
    const int EP = (E + 15) & ~15;

    char* w = (char*)d_ws;
    int* deg    = (int*)w;  w += (size_t)NP * 4;
    int* rp     = (int*)w;  w += (size_t)(NP + 64) * 4;
    int* cursor = (int*)w;  w += (size_t)NP * 4;
    int* colA   = (int*)w;  w += (size_t)EP * 4;
    float* meanb = (float*)w;  w += (size_t)N * 128 * 4;
    float* h     = (float*)w;  w += (size_t)N * 128 * 4;
    float* segb  = (float*)w;  w += (size_t)N * 128 * 4;  // xs, then hs (reuse)

    const bool use_seg =
        ((size_t)((char*)(segb + (size_t)N * 128) - (char*)d_ws)) <= ws_size;

    float* out_mu = (float*)d_out;
    float* out_ls = out_mu + (size_t)N * OUTW;

    // CSR build
    k_zero<<<(N + 255) / 256, 256, 0, stream>>>(deg, N);
    k_degree<<<(E + 255) / 256, 256, 0, stream>>>(dstI, deg, E);
    k_scan<<<1, 1024, 0, stream>>>(deg, rp, cursor, N);
    k_fill<<<(E + 255) / 256, 256, 0, stream>>>(srcI, dstI, cursor, colA, E);

    const int ablocks = (N + 3) / 4;
    const int gblocks = (N + 31) / 32;

    if (use_seg) {
        const dim3 agrid(ablocks, 8);
        // layer 1
        k_repack<<<(N * 32 + 255) / 256, 256, 0, stream>>>(x, segb, N);
        k_agg_seg<<<agrid, 256, 0, stream>>>(segb, rp, colA, meanb, N);
        k_gemm<0, 1><<<gblocks, 256, 0, stream>>>(
            meanb, x, W1_l, nullptr, W1_r, nullptr, b1, nullptr,
            h, nullptr, segb, N);  // segb becomes hs
        // layer 2
        k_agg_seg<<<agrid, 256, 0, stream>>>(segb, rp, colA, meanb, N);
        k_gemm<1, 0><<<gblocks, 256, 0, stream>>>(
            meanb, h, Wmu_l, Wls_l, Wmu_r, Wls_r, bmu, bls,
            out_mu, out_ls, nullptr, N);
    } else {
        // fallback: proven row-major gather path
        k_agg_row<<<ablocks, 256, 0, stream>>>(x, rp, colA, meanb, N);
        k_gemm<0, 0><<<gblocks, 256, 0, stream>>>(
            meanb, x, W1_l, nullptr, W1_r, nullptr, b1, nullptr,
            h, nullptr, nullptr, N);
        k_agg_row<<<ablocks, 256, 0, stream>>>(h, rp, colA, meanb, N);
        k_gemm<1, 0><<<gblocks, 256, 0, stream>>>(
            meanb, h, Wmu_l, Wls_l, Wmu_r, Wls_r, bmu, bls,
            out_mu, out_ls, nullptr, N);
    }
}

// Round 7
// 593.997 us; speedup vs baseline: 1.0835x; 1.0835x over previous
//
#include <hip/hip_runtime.h>

#define NODES_CH 128   // IN_CH == HID == 128
#define OUTW 64

// ---------------- CSR build ----------------

__global__ void k_zero(int* __restrict__ p, int n) {
    int i = blockIdx.x * blockDim.x + threadIdx.x;
    if (i < n) p[i] = 0;
}

__global__ void k_degree(const int* __restrict__ dstI, int* __restrict__ deg, int E) {
    int e = blockIdx.x * blockDim.x + threadIdx.x;
    if (e < E) atomicAdd(&deg[dstI[e]], 1);
}

// single-block exclusive scan; also inits cursor
__global__ __launch_bounds__(1024)
void k_scan(const int* __restrict__ deg, int* __restrict__ rp,
            int* __restrict__ cursor, int n) {
    __shared__ int wsum[16];
    int tid  = threadIdx.x;
    int lane = tid & 63;
    int wid  = tid >> 6;
    int carry = 0;
    for (int base = 0; base < n; base += 1024) {
        int i = base + tid;
        int v = (i < n) ? deg[i] : 0;
        int x = v;
        #pragma unroll
        for (int off = 1; off < 64; off <<= 1) {
            int t = __shfl_up(x, off, 64);
            if (lane >= off) x += t;
        }
        if (lane == 63) wsum[wid] = x;
        __syncthreads();
        if (wid == 0) {
            int y = (lane < 16) ? wsum[lane] : 0;
            #pragma unroll
            for (int off = 1; off < 16; off <<= 1) {
                int t = __shfl_up(y, off, 64);
                if (lane >= off) y += t;
            }
            if (lane < 16) wsum[lane] = y;
        }
        __syncthreads();
        int woff  = (wid > 0) ? wsum[wid - 1] : 0;
        int incl  = x + woff;
        int total = wsum[15];
        if (i < n) {
            int ex = carry + incl - v;
            rp[i] = ex;
            cursor[i] = ex;
        }
        carry += total;
        __syncthreads();  // protect wsum before next chunk overwrites
    }
    if (tid == 0) rp[n] = carry;
}

__global__ void k_fill(const int* __restrict__ srcI, const int* __restrict__ dstI,
                       int* __restrict__ cursor, int* __restrict__ colA, int E) {
    int e = blockIdx.x * blockDim.x + threadIdx.x;
    if (e < E) {
        int d = dstI[e];
        int p = atomicAdd(&cursor[d], 1);
        colA[p] = srcI[e];
    }
}

// ---------------- repack row-major [N][128] -> seg-major [8][N][16] ----------------
// blockIdx.y = segment; writes fully coalesced (R6's scattered writes cost ~30us).
__global__ void k_repack(const float* __restrict__ X, float* __restrict__ XS, int n) {
    int i = blockIdx.x * blockDim.x + threadIdx.x;  // float4 idx within segment
    if (i >= n * 4) return;
    int seg  = blockIdx.y;
    int node = i >> 2, c4i = i & 3;
    float4 v = ((const float4*)X)[(size_t)node * 32 + seg * 4 + c4i];
    ((float4*)XS)[(size_t)seg * n * 4 + i] = v;
}

// ---------------- segmented mean aggregation, XCD-pinned ----------------
// seg = blockIdx.x & 7: consecutive blocks round-robin across the 8 XCDs,
// so XCD k works ONLY segment k's 3.2 MB slice -> slice stays L2-resident.
// (R6's blockIdx.y=seg put all XCDs on the same slice: 8x compulsory refetch,
// FETCH 128 MB. If round-robin assumption is wrong, FETCH stays ~128 MB.)
// Wave per node-segment: 8 edge slots x 8 float2 channels (16 floats/seg).
__global__ __launch_bounds__(256)
void k_agg_seg(const float* __restrict__ XS, const int* __restrict__ rp,
               const int* __restrict__ colA, float* __restrict__ out, int n) {
    int b = blockIdx.x;
    int seg = b & 7;
    int node = ((b >> 3) << 2) + (threadIdx.x >> 6);
    if (node >= n) return;
    int lane = threadIdx.x & 63;
    int es = lane >> 3;      // 8 edge slots
    int ch = lane & 7;       // 8 float2 channels
    int beg = rp[node], end = rp[node + 1];
    const float2* __restrict__ XS2 = (const float2*)XS;  // [8][n][8]
    size_t segbase = (size_t)seg * n * 8;
    float2 s = make_float2(0.f, 0.f);
    for (int e = beg + es; e < end; e += 8) {
        int c = colA[e];
        float2 v = XS2[segbase + (size_t)c * 8 + ch];
        s.x += v.x; s.y += v.y;
    }
    s.x += __shfl_xor(s.x, 8);  s.y += __shfl_xor(s.y, 8);
    s.x += __shfl_xor(s.x, 16); s.y += __shfl_xor(s.y, 16);
    s.x += __shfl_xor(s.x, 32); s.y += __shfl_xor(s.y, 32);
    if (es == 0) {
        float inv = 1.f / (float)((end > beg) ? (end - beg) : 1);
        ((float2*)out)[(size_t)node * 64 + seg * 8 + ch] =
            make_float2(s.x * inv, s.y * inv);
    }
}

// ---------------- fallback row-major aggregation (proven R5 path) ----------------
__global__ __launch_bounds__(256)
void k_agg_row(const float* __restrict__ X, const int* __restrict__ rp,
               const int* __restrict__ colA, float* __restrict__ out, int n) {
    int node = (blockIdx.x << 2) + (threadIdx.x >> 6);
    if (node >= n) return;
    int lane = threadIdx.x & 63;
    int eh = lane >> 5;
    int c4 = lane & 31;
    int beg = rp[node], end = rp[node + 1];
    const float4* __restrict__ X4 = (const float4*)X;
    float4 s = make_float4(0.f, 0.f, 0.f, 0.f);
    int e = beg + eh;
    for (; e + 2 < end; e += 4) {
        int c0 = colA[e];
        int c1 = colA[e + 2];
        float4 v0 = X4[(size_t)c0 * 32 + c4];
        float4 v1 = X4[(size_t)c1 * 32 + c4];
        s.x += v0.x + v1.x; s.y += v0.y + v1.y;
        s.z += v0.z + v1.z; s.w += v0.w + v1.w;
    }
    if (e < end) {
        int c0 = colA[e];
        float4 v0 = X4[(size_t)c0 * 32 + c4];
        s.x += v0.x; s.y += v0.y; s.z += v0.z; s.w += v0.w;
    }
    s.x += __shfl_xor(s.x, 32);
    s.y += __shfl_xor(s.y, 32);
    s.z += __shfl_xor(s.z, 32);
    s.w += __shfl_xor(s.w, 32);
    if (eh == 0) {
        float inv = 1.f / (float)((end > beg) ? (end - beg) : 1);
        ((float4*)out)[(size_t)node * 32 + c4] =
            make_float4(s.x * inv, s.y * inv, s.z * inv, s.w * inv);
    }
}

// ---------------- fused SAGE linear, A-tile + W in LDS ----------------
// R5-proven body (acc[4][8], 72 VGPR, zero W-conflicts, "unroll 2" only),
// plus A staged in LDS: inner k-loop is pure LDS+FMA -> no global latency
// to hide (R5 was latency-bound: VALU 25%, Occ 20%, 124 us).
// Alds padded +4 floats/row (stride 528 B): 4-row ds_read_b128 hits banks
// offset by 4 -> conflict-free. LDS 50 KB -> 3 blocks/CU.
// MODE 0 (+relu, 128 cols): SEGOUT writes seg-major copy for next agg.
// MODE 1: [Wmu|Wls] virtual 128 cols -> split 64-col outputs.
template <int MODE, int SEGOUT>
__global__ __launch_bounds__(256, 2)
void k_gemm(const float* __restrict__ A0, const float* __restrict__ A1,
            const float* __restrict__ Wa0, const float* __restrict__ Wb0,
            const float* __restrict__ Wa1, const float* __restrict__ Wb1,
            const float* __restrict__ ba, const float* __restrict__ bb,
            float* __restrict__ out0, float* __restrict__ out1,
            float* __restrict__ outseg, int N) {
    __shared__ float Alds[64 * 132];  // 33.8 KiB, +4 pad
    __shared__ float Wlds[32 * 128];  // 16 KiB
    const int tid = threadIdx.x;
    const int cg  = tid & 15;
    const int rg  = tid >> 4;
    const int rbase = blockIdx.x * 64 + rg * 4;

    float acc[4][8];
    #pragma unroll
    for (int r = 0; r < 4; r++)
        #pragma unroll
        for (int c = 0; c < 8; c++) acc[r][c] = 0.f;

    for (int phase = 0; phase < 2; ++phase) {
        const float* __restrict__ A = phase ? A1 : A0;
        __syncthreads();  // previous phase's Alds reads done
        for (int j = tid; j < 2048; j += 256) {
            int row = j >> 5, c4 = j & 31;
            int grow = blockIdx.x * 64 + row;
            float4 v = (grow < N)
                ? *(const float4*)(A + (size_t)grow * 128 + c4 * 4)
                : make_float4(0.f, 0.f, 0.f, 0.f);
            *(float4*)(Alds + row * 132 + c4 * 4) = v;
        }
        for (int kc = 0; kc < 4; ++kc) {
            __syncthreads();  // covers Alds writes (kc=0) and prior Wlds reads
            if (MODE == 0) {
                const float* __restrict__ W = phase ? Wa1 : Wa0;  // [128][128]
                for (int i = tid; i < 1024; i += 256) {
                    int kr = i >> 5, c4 = i & 31;
                    ((float4*)Wlds)[i] =
                        *(const float4*)(W + (size_t)(kc * 32 + kr) * 128 + c4 * 4);
                }
            } else {
                const float* __restrict__ WA = phase ? Wa1 : Wa0;  // [128][64] mu
                const float* __restrict__ WB = phase ? Wb1 : Wb0;  // [128][64] ls
                for (int i = tid; i < 1024; i += 256) {
                    int kr = i >> 5, c4 = i & 31;
                    const float* s = (c4 < 16)
                        ? (WA + (size_t)(kc * 32 + kr) * 64 + c4 * 4)
                        : (WB + (size_t)(kc * 32 + kr) * 64 + (c4 - 16) * 4);
                    ((float4*)Wlds)[i] = *(const float4*)s;
                }
            }
            __syncthreads();
            #pragma unroll 2
            for (int k = 0; k < 32; k += 4) {
                float4 a[4];
                #pragma unroll
                for (int r = 0; r < 4; r++)
                    a[r] = *(const float4*)(Alds + (rg * 4 + r) * 132 + kc * 32 + k);
                #pragma unroll
                for (int kk = 0; kk < 4; kk++) {
                    float4 w0 = *(const float4*)(Wlds + (k + kk) * 128 + cg * 4);
                    float4 w1 = *(const float4*)(Wlds + (k + kk) * 128 + 64 + cg * 4);
                    #pragma unroll
                    for (int r = 0; r < 4; r++) {
                        float av = (kk == 0) ? a[r].x : (kk == 1) ? a[r].y
                                 : (kk == 2) ? a[r].z : a[r].w;
                        acc[r][0] += av * w0.x;
                        acc[r][1] += av * w0.y;
                        acc[r][2] += av * w0.z;
                        acc[r][3] += av * w0.w;
                        acc[r][4] += av * w1.x;
                        acc[r][5] += av * w1.y;
                        acc[r][6] += av * w1.z;
                        acc[r][7] += av * w1.w;
                    }
                }
            }
        }
    }

    // epilogue
    if (MODE == 0) {
        const float4 bv0 = *(const float4*)(ba + cg * 4);
        const float4 bv1 = *(const float4*)(ba + 64 + cg * 4);
        #pragma unroll
        for (int r = 0; r < 4; r++) {
            int row = rbase + r;
            if (row >= N) continue;
            float4 v0, v1;
            v0.x = fmaxf(acc[r][0] + bv0.x, 0.f);
            v0.y = fmaxf(acc[r][1] + bv0.y, 0.f);
            v0.z = fmaxf(acc[r][2] + bv0.z, 0.f);
            v0.w = fmaxf(acc[r][3] + bv0.w, 0.f);
            v1.x = fmaxf(acc[r][4] + bv1.x, 0.f);
            v1.y = fmaxf(acc[r][5] + bv1.y, 0.f);
            v1.z = fmaxf(acc[r][6] + bv1.z, 0.f);
            v1.w = fmaxf(acc[r][7] + bv1.w, 0.f);
            *(float4*)(out0 + (size_t)row * 128 + cg * 4) = v0;
            *(float4*)(out0 + (size_t)row * 128 + 64 + cg * 4) = v1;
            if (SEGOUT) {
                *(float4*)(outseg + (size_t)(cg >> 2) * N * 16
                           + (size_t)row * 16 + (cg & 3) * 4) = v0;
                *(float4*)(outseg + (size_t)(4 + (cg >> 2)) * N * 16
                           + (size_t)row * 16 + (cg & 3) * 4) = v1;
            }
        }
    } else {
        const float4 bm = *(const float4*)(ba + cg * 4);
        const float4 bl = *(const float4*)(bb + cg * 4);
        #pragma unroll
        for (int r = 0; r < 4; r++) {
            int row = rbase + r;
            if (row >= N) continue;
            float4 vm, vl;
            vm.x = acc[r][0] + bm.x; vm.y = acc[r][1] + bm.y;
            vm.z = acc[r][2] + bm.z; vm.w = acc[r][3] + bm.w;
            vl.x = acc[r][4] + bl.x; vl.y = acc[r][5] + bl.y;
            vl.z = acc[r][6] + bl.z; vl.w = acc[r][7] + bl.w;
            *(float4*)(out0 + (size_t)row * 64 + cg * 4) = vm;
            *(float4*)(out1 + (size_t)row * 64 + cg * 4) = vl;
        }
    }
}

// ---------------- launch ----------------

extern "C" void kernel_launch(void* const* d_in, const int* in_sizes, int n_in,
                              void* d_out, int out_size, void* d_ws, size_t ws_size,
                              hipStream_t stream) {
    const float* x     = (const float*)d_in[0];
    const int*   ei    = (const int*)d_in[1];
    const float* W1_l  = (const float*)d_in[2];
    const float* b1    = (const float*)d_in[3];
    const float* W1_r  = (const float*)d_in[4];
    const float* Wmu_l = (const float*)d_in[5];
    const float* bmu   = (const float*)d_in[6];
    const float* Wmu_r = (const float*)d_in[7];
    const float* Wls_l = (const float*)d_in[8];
    const float* bls   = (const float*)d_in[9];
    const float* Wls_r = (const float*)d_in[10];

    const int N = in_sizes[0] / NODES_CH;  // 50000
    const int E = in_sizes[1] / 2;         // 800000
    const int* srcI = ei;
    const int* dstI = ei + E;

    const int NP = (N + 63) & ~63;
    const int EP = (E + 15) & ~15;

    char* w = (char*)d_ws;
    int* deg    = (int*)w;  w += (size_t)NP * 4;
    int* rp     = (int*)w;  w += (size_t)(NP + 64) * 4;
    int* cursor = (int*)w;  w += (size_t)NP * 4;
    int* colA   = (int*)w;  w += (size_t)EP * 4;
    float* meanb = (float*)w;  w += (size_t)N * 128 * 4;
    float* h     = (float*)w;  w += (size_t)N * 128 * 4;
    float* segb  = (float*)w;  w += (size_t)N * 128 * 4;  // xs, then hs (reuse)

    const bool use_seg =
        ((size_t)((char*)(segb + (size_t)N * 128) - (char*)d_ws)) <= ws_size;

    float* out_mu = (float*)d_out;
    float* out_ls = out_mu + (size_t)N * OUTW;

    // CSR build
    k_zero<<<(N + 255) / 256, 256, 0, stream>>>(deg, N);
    k_degree<<<(E + 255) / 256, 256, 0, stream>>>(dstI, deg, E);
    k_scan<<<1, 1024, 0, stream>>>(deg, rp, cursor, N);
    k_fill<<<(E + 255) / 256, 256, 0, stream>>>(srcI, dstI, cursor, colA, E);

    const int ablocks = (N + 3) / 4;
    const int gblocks = (N + 63) / 64;

    if (use_seg) {
        // layer 1
        k_repack<<<dim3((N * 4 + 255) / 256, 8), 256, 0, stream>>>(x, segb, N);
        k_agg_seg<<<ablocks * 8, 256, 0, stream>>>(segb, rp, colA, meanb, N);
        k_gemm<0, 1><<<gblocks, 256, 0, stream>>>(
            meanb, x, W1_l, nullptr, W1_r, nullptr, b1, nullptr,
            h, nullptr, segb, N);  // segb becomes hs
        // layer 2
        k_agg_seg<<<ablocks * 8, 256, 0, stream>>>(segb, rp, colA, meanb, N);
        k_gemm<1, 0><<<gblocks, 256, 0, stream>>>(
            meanb, h, Wmu_l, Wls_l, Wmu_r, Wls_r, bmu, bls,
            out_mu, out_ls, nullptr, N);
    } else {
        // fallback: proven row-major gather path
        k_agg_row<<<ablocks, 256, 0, stream>>>(x, rp, colA, meanb, N);
        k_gemm<0, 0><<<gblocks, 256, 0, stream>>>(
            meanb, x, W1_l, nullptr, W1_r, nullptr, b1, nullptr,
            h, nullptr, nullptr, N);
        k_agg_row<<<ablocks, 256, 0, stream>>>(h, rp, colA, meanb, N);
        k_gemm<1, 0><<<gblocks, 256, 0, stream>>>(
            meanb, h, Wmu_l, Wls_l, Wmu_r, Wls_r, bmu, bls,
            out_mu, out_ls, nullptr, N);
    }
}

// Round 8
// 553.880 us; speedup vs baseline: 1.1620x; 1.0724x over previous
//
#include <hip/hip_runtime.h>

#define NODES_CH 128   // IN_CH == HID == 128
#define OUTW 64

// ---------------- CSR build ----------------

__global__ void k_zero(int* __restrict__ p, int n) {
    int i = blockIdx.x * blockDim.x + threadIdx.x;
    if (i < n) p[i] = 0;
}

__global__ void k_degree(const int* __restrict__ dstI, int* __restrict__ deg, int E) {
    int e = blockIdx.x * blockDim.x + threadIdx.x;
    if (e < E) atomicAdd(&deg[dstI[e]], 1);
}

// single-block exclusive scan; also inits cursor
__global__ __launch_bounds__(1024)
void k_scan(const int* __restrict__ deg, int* __restrict__ rp,
            int* __restrict__ cursor, int n) {
    __shared__ int wsum[16];
    int tid  = threadIdx.x;
    int lane = tid & 63;
    int wid  = tid >> 6;
    int carry = 0;
    for (int base = 0; base < n; base += 1024) {
        int i = base + tid;
        int v = (i < n) ? deg[i] : 0;
        int x = v;
        #pragma unroll
        for (int off = 1; off < 64; off <<= 1) {
            int t = __shfl_up(x, off, 64);
            if (lane >= off) x += t;
        }
        if (lane == 63) wsum[wid] = x;
        __syncthreads();
        if (wid == 0) {
            int y = (lane < 16) ? wsum[lane] : 0;
            #pragma unroll
            for (int off = 1; off < 16; off <<= 1) {
                int t = __shfl_up(y, off, 64);
                if (lane >= off) y += t;
            }
            if (lane < 16) wsum[lane] = y;
        }
        __syncthreads();
        int woff  = (wid > 0) ? wsum[wid - 1] : 0;
        int incl  = x + woff;
        int total = wsum[15];
        if (i < n) {
            int ex = carry + incl - v;
            rp[i] = ex;
            cursor[i] = ex;
        }
        carry += total;
        __syncthreads();  // protect wsum before next chunk overwrites
    }
    if (tid == 0) rp[n] = carry;
}

__global__ void k_fill(const int* __restrict__ srcI, const int* __restrict__ dstI,
                       int* __restrict__ cursor, int* __restrict__ colA, int E) {
    int e = blockIdx.x * blockDim.x + threadIdx.x;
    if (e < E) {
        int d = dstI[e];
        int p = atomicAdd(&cursor[d], 1);
        colA[p] = srcI[e];
    }
}

// ---------------- repack row-major [N][128] -> seg-major [8][N][16] ----------------
// blockIdx.y = segment; writes fully coalesced.
__global__ void k_repack(const float* __restrict__ X, float* __restrict__ XS, int n) {
    int i = blockIdx.x * blockDim.x + threadIdx.x;  // float4 idx within segment
    if (i >= n * 4) return;
    int seg  = blockIdx.y;
    int node = i >> 2, c4i = i & 3;
    float4 v = ((const float4*)X)[(size_t)node * 32 + seg * 4 + c4i];
    ((float4*)XS)[(size_t)seg * n * 4 + i] = v;
}

// ---------------- segmented mean aggregation, XCD-pinned, 16-slot float4 ----------------
// seg = blockIdx.x & 7: consecutive blocks round-robin across 8 XCDs -> XCD k
// keeps only slice k (3.2 MB) in its L2 (R7: FETCH 128->36 MB, confirmed).
// R7 was latency-bound (VALU 45%, L2-BW 11%): 8 slots -> avg 2.5 dependent
// gather rounds/wave. Now 16 edge slots x 4 float4 channels: avg degree 16
// -> ~1 round; pairs loop keeps 2 loads in flight for deg>16.
__global__ __launch_bounds__(256)
void k_agg_seg(const float* __restrict__ XS, const int* __restrict__ rp,
               const int* __restrict__ colA, float* __restrict__ out, int n) {
    int b = blockIdx.x;
    int seg = b & 7;
    int node = ((b >> 3) << 2) + (threadIdx.x >> 6);
    if (node >= n) return;
    int lane = threadIdx.x & 63;
    int es  = lane >> 2;     // 16 edge slots
    int ch4 = lane & 3;      // 4 float4 channels (16 floats/segment)
    int beg = rp[node], end = rp[node + 1];
    const float4* __restrict__ XS4 = (const float4*)XS;  // [8][n][4]
    size_t segbase4 = (size_t)seg * n * 4;
    float4 s = make_float4(0.f, 0.f, 0.f, 0.f);
    int e = beg + es;
    for (; e + 16 < end; e += 32) {   // 2 independent gathers in flight
        int c0 = colA[e];
        int c1 = colA[e + 16];
        float4 v0 = XS4[segbase4 + (size_t)c0 * 4 + ch4];
        float4 v1 = XS4[segbase4 + (size_t)c1 * 4 + ch4];
        s.x += v0.x + v1.x; s.y += v0.y + v1.y;
        s.z += v0.z + v1.z; s.w += v0.w + v1.w;
    }
    if (e < end) {
        int c0 = colA[e];
        float4 v0 = XS4[segbase4 + (size_t)c0 * 4 + ch4];
        s.x += v0.x; s.y += v0.y; s.z += v0.z; s.w += v0.w;
    }
    #pragma unroll
    for (int off = 4; off <= 32; off <<= 1) {
        s.x += __shfl_xor(s.x, off);
        s.y += __shfl_xor(s.y, off);
        s.z += __shfl_xor(s.z, off);
        s.w += __shfl_xor(s.w, off);
    }
    if (es == 0) {
        float inv = 1.f / (float)((end > beg) ? (end - beg) : 1);
        ((float4*)out)[(size_t)node * 32 + seg * 4 + ch4] =
            make_float4(s.x * inv, s.y * inv, s.z * inv, s.w * inv);
    }
}

// ---------------- fallback row-major aggregation (proven R5 path) ----------------
__global__ __launch_bounds__(256)
void k_agg_row(const float* __restrict__ X, const int* __restrict__ rp,
               const int* __restrict__ colA, float* __restrict__ out, int n) {
    int node = (blockIdx.x << 2) + (threadIdx.x >> 6);
    if (node >= n) return;
    int lane = threadIdx.x & 63;
    int eh = lane >> 5;
    int c4 = lane & 31;
    int beg = rp[node], end = rp[node + 1];
    const float4* __restrict__ X4 = (const float4*)X;
    float4 s = make_float4(0.f, 0.f, 0.f, 0.f);
    int e = beg + eh;
    for (; e + 2 < end; e += 4) {
        int c0 = colA[e];
        int c1 = colA[e + 2];
        float4 v0 = X4[(size_t)c0 * 32 + c4];
        float4 v1 = X4[(size_t)c1 * 32 + c4];
        s.x += v0.x + v1.x; s.y += v0.y + v1.y;
        s.z += v0.z + v1.z; s.w += v0.w + v1.w;
    }
    if (e < end) {
        int c0 = colA[e];
        float4 v0 = X4[(size_t)c0 * 32 + c4];
        s.x += v0.x; s.y += v0.y; s.z += v0.z; s.w += v0.w;
    }
    s.x += __shfl_xor(s.x, 32);
    s.y += __shfl_xor(s.y, 32);
    s.z += __shfl_xor(s.z, 32);
    s.w += __shfl_xor(s.w, 32);
    if (eh == 0) {
        float inv = 1.f / (float)((end > beg) ? (end - beg) : 1);
        ((float4*)out)[(size_t)node * 32 + c4] =
            make_float4(s.x * inv, s.y * inv, s.z * inv, s.w * inv);
    }
}

// ---------------- fused SAGE linear, A-tile + W in LDS (R7, frozen) ----------------
template <int MODE, int SEGOUT>
__global__ __launch_bounds__(256, 2)
void k_gemm(const float* __restrict__ A0, const float* __restrict__ A1,
            const float* __restrict__ Wa0, const float* __restrict__ Wb0,
            const float* __restrict__ Wa1, const float* __restrict__ Wb1,
            const float* __restrict__ ba, const float* __restrict__ bb,
            float* __restrict__ out0, float* __restrict__ out1,
            float* __restrict__ outseg, int N) {
    __shared__ float Alds[64 * 132];  // 33.8 KiB, +4 pad
    __shared__ float Wlds[32 * 128];  // 16 KiB
    const int tid = threadIdx.x;
    const int cg  = tid & 15;
    const int rg  = tid >> 4;
    const int rbase = blockIdx.x * 64 + rg * 4;

    float acc[4][8];
    #pragma unroll
    for (int r = 0; r < 4; r++)
        #pragma unroll
        for (int c = 0; c < 8; c++) acc[r][c] = 0.f;

    for (int phase = 0; phase < 2; ++phase) {
        const float* __restrict__ A = phase ? A1 : A0;
        __syncthreads();  // previous phase's Alds reads done
        for (int j = tid; j < 2048; j += 256) {
            int row = j >> 5, c4 = j & 31;
            int grow = blockIdx.x * 64 + row;
            float4 v = (grow < N)
                ? *(const float4*)(A + (size_t)grow * 128 + c4 * 4)
                : make_float4(0.f, 0.f, 0.f, 0.f);
            *(float4*)(Alds + row * 132 + c4 * 4) = v;
        }
        for (int kc = 0; kc < 4; ++kc) {
            __syncthreads();  // covers Alds writes (kc=0) and prior Wlds reads
            if (MODE == 0) {
                const float* __restrict__ W = phase ? Wa1 : Wa0;  // [128][128]
                for (int i = tid; i < 1024; i += 256) {
                    int kr = i >> 5, c4 = i & 31;
                    ((float4*)Wlds)[i] =
                        *(const float4*)(W + (size_t)(kc * 32 + kr) * 128 + c4 * 4);
                }
            } else {
                const float* __restrict__ WA = phase ? Wa1 : Wa0;  // [128][64] mu
                const float* __restrict__ WB = phase ? Wb1 : Wb0;  // [128][64] ls
                for (int i = tid; i < 1024; i += 256) {
                    int kr = i >> 5, c4 = i & 31;
                    const float* s = (c4 < 16)
                        ? (WA + (size_t)(kc * 32 + kr) * 64 + c4 * 4)
                        : (WB + (size_t)(kc * 32 + kr) * 64 + (c4 - 16) * 4);
                    ((float4*)Wlds)[i] = *(const float4*)s;
                }
            }
            __syncthreads();
            #pragma unroll 2
            for (int k = 0; k < 32; k += 4) {
                float4 a[4];
                #pragma unroll
                for (int r = 0; r < 4; r++)
                    a[r] = *(const float4*)(Alds + (rg * 4 + r) * 132 + kc * 32 + k);
                #pragma unroll
                for (int kk = 0; kk < 4; kk++) {
                    float4 w0 = *(const float4*)(Wlds + (k + kk) * 128 + cg * 4);
                    float4 w1 = *(const float4*)(Wlds + (k + kk) * 128 + 64 + cg * 4);
                    #pragma unroll
                    for (int r = 0; r < 4; r++) {
                        float av = (kk == 0) ? a[r].x : (kk == 1) ? a[r].y
                                 : (kk == 2) ? a[r].z : a[r].w;
                        acc[r][0] += av * w0.x;
                        acc[r][1] += av * w0.y;
                        acc[r][2] += av * w0.z;
                        acc[r][3] += av * w0.w;
                        acc[r][4] += av * w1.x;
                        acc[r][5] += av * w1.y;
                        acc[r][6] += av * w1.z;
                        acc[r][7] += av * w1.w;
                    }
                }
            }
        }
    }

    // epilogue
    if (MODE == 0) {
        const float4 bv0 = *(const float4*)(ba + cg * 4);
        const float4 bv1 = *(const float4*)(ba + 64 + cg * 4);
        #pragma unroll
        for (int r = 0; r < 4; r++) {
            int row = rbase + r;
            if (row >= N) continue;
            float4 v0, v1;
            v0.x = fmaxf(acc[r][0] + bv0.x, 0.f);
            v0.y = fmaxf(acc[r][1] + bv0.y, 0.f);
            v0.z = fmaxf(acc[r][2] + bv0.z, 0.f);
            v0.w = fmaxf(acc[r][3] + bv0.w, 0.f);
            v1.x = fmaxf(acc[r][4] + bv1.x, 0.f);
            v1.y = fmaxf(acc[r][5] + bv1.y, 0.f);
            v1.z = fmaxf(acc[r][6] + bv1.z, 0.f);
            v1.w = fmaxf(acc[r][7] + bv1.w, 0.f);
            *(float4*)(out0 + (size_t)row * 128 + cg * 4) = v0;
            *(float4*)(out0 + (size_t)row * 128 + 64 + cg * 4) = v1;
            if (SEGOUT) {
                *(float4*)(outseg + (size_t)(cg >> 2) * N * 16
                           + (size_t)row * 16 + (cg & 3) * 4) = v0;
                *(float4*)(outseg + (size_t)(4 + (cg >> 2)) * N * 16
                           + (size_t)row * 16 + (cg & 3) * 4) = v1;
            }
        }
    } else {
        const float4 bm = *(const float4*)(ba + cg * 4);
        const float4 bl = *(const float4*)(bb + cg * 4);
        #pragma unroll
        for (int r = 0; r < 4; r++) {
            int row = rbase + r;
            if (row >= N) continue;
            float4 vm, vl;
            vm.x = acc[r][0] + bm.x; vm.y = acc[r][1] + bm.y;
            vm.z = acc[r][2] + bm.z; vm.w = acc[r][3] + bm.w;
            vl.x = acc[r][4] + bl.x; vl.y = acc[r][5] + bl.y;
            vl.z = acc[r][6] + bl.z; vl.w = acc[r][7] + bl.w;
            *(float4*)(out0 + (size_t)row * 64 + cg * 4) = vm;
            *(float4*)(out1 + (size_t)row * 64 + cg * 4) = vl;
        }
    }
}

// ---------------- launch ----------------

extern "C" void kernel_launch(void* const* d_in, const int* in_sizes, int n_in,
                              void* d_out, int out_size, void* d_ws, size_t ws_size,
                              hipStream_t stream) {
    const float* x     = (const float*)d_in[0];
    const int*   ei    = (const int*)d_in[1];
    const float* W1_l  = (const float*)d_in[2];
    const float* b1    = (const float*)d_in[3];
    const float* W1_r  = (const float*)d_in[4];
    const float* Wmu_l = (const float*)d_in[5];
    const float* bmu   = (const float*)d_in[6];
    const float* Wmu_r = (const float*)d_in[7];
    const float* Wls_l = (const float*)d_in[8];
    const float* bls   = (const float*)d_in[9];
    const float* Wls_r = (const float*)d_in[10];

    const int N = in_sizes[0] / NODES_CH;  // 50000
    const int E = in_sizes[1] / 2;         // 800000
    const int* srcI = ei;
    const int* dstI = ei + E;

    const int NP = (N + 63) & ~63;
    const int EP = (E + 15) & ~15;

    char* w = (char*)d_ws;
    int* deg    = (int*)w;  w += (size_t)NP * 4;
    int* rp     = (int*)w;  w += (size_t)(NP + 64) * 4;
    int* cursor = (int*)w;  w += (size_t)NP * 4;
    int* colA   = (int*)w;  w += (size_t)EP * 4;
    float* meanb = (float*)w;  w += (size_t)N * 128 * 4;
    float* h     = (float*)w;  w += (size_t)N * 128 * 4;
    float* segb  = (float*)w;  w += (size_t)N * 128 * 4;  // xs, then hs (reuse)

    const bool use_seg =
        ((size_t)((char*)(segb + (size_t)N * 128) - (char*)d_ws)) <= ws_size;

    float* out_mu = (float*)d_out;
    float* out_ls = out_mu + (size_t)N * OUTW;

    // CSR build
    k_zero<<<(N + 255) / 256, 256, 0, stream>>>(deg, N);
    k_degree<<<(E + 255) / 256, 256, 0, stream>>>(dstI, deg, E);
    k_scan<<<1, 1024, 0, stream>>>(deg, rp, cursor, N);
    k_fill<<<(E + 255) / 256, 256, 0, stream>>>(srcI, dstI, cursor, colA, E);

    const int ablocks = (N + 3) / 4;
    const int gblocks = (N + 63) / 64;

    if (use_seg) {
        // layer 1
        k_repack<<<dim3((N * 4 + 255) / 256, 8), 256, 0, stream>>>(x, segb, N);
        k_agg_seg<<<ablocks * 8, 256, 0, stream>>>(segb, rp, colA, meanb, N);
        k_gemm<0, 1><<<gblocks, 256, 0, stream>>>(
            meanb, x, W1_l, nullptr, W1_r, nullptr, b1, nullptr,
            h, nullptr, segb, N);  // segb becomes hs
        // layer 2
        k_agg_seg<<<ablocks * 8, 256, 0, stream>>>(segb, rp, colA, meanb, N);
        k_gemm<1, 0><<<gblocks, 256, 0, stream>>>(
            meanb, h, Wmu_l, Wls_l, Wmu_r, Wls_r, bmu, bls,
            out_mu, out_ls, nullptr, N);
    } else {
        // fallback: proven row-major gather path
        k_agg_row<<<ablocks, 256, 0, stream>>>(x, rp, colA, meanb, N);
        k_gemm<0, 0><<<gblocks, 256, 0, stream>>>(
            meanb, x, W1_l, nullptr, W1_r, nullptr, b1, nullptr,
            h, nullptr, nullptr, N);
        k_agg_row<<<ablocks, 256, 0, stream>>>(h, rp, colA, meanb, N);
        k_gemm<1, 0><<<gblocks, 256, 0, stream>>>(
            meanb, h, Wmu_l, Wls_l, Wmu_r, Wls_r, bmu, bls,
            out_mu, out_ls, nullptr, N);
    }
}

// Round 9
// 527.084 us; speedup vs baseline: 1.2210x; 1.0508x over previous
//
#include <hip/hip_runtime.h>

#define NODES_CH 128   // IN_CH == HID == 128
#define OUTW 64

// ---------------- CSR build ----------------

__global__ void k_zero(int* __restrict__ p, int n) {
    int i = blockIdx.x * blockDim.x + threadIdx.x;
    if (i < n) p[i] = 0;
}

__global__ void k_degree(const int* __restrict__ dstI, int* __restrict__ deg, int E) {
    int e = blockIdx.x * blockDim.x + threadIdx.x;
    if (e < E) atomicAdd(&deg[dstI[e]], 1);
}

// single-block exclusive scan; also inits cursor
__global__ __launch_bounds__(1024)
void k_scan(const int* __restrict__ deg, int* __restrict__ rp,
            int* __restrict__ cursor, int n) {
    __shared__ int wsum[16];
    int tid  = threadIdx.x;
    int lane = tid & 63;
    int wid  = tid >> 6;
    int carry = 0;
    for (int base = 0; base < n; base += 1024) {
        int i = base + tid;
        int v = (i < n) ? deg[i] : 0;
        int x = v;
        #pragma unroll
        for (int off = 1; off < 64; off <<= 1) {
            int t = __shfl_up(x, off, 64);
            if (lane >= off) x += t;
        }
        if (lane == 63) wsum[wid] = x;
        __syncthreads();
        if (wid == 0) {
            int y = (lane < 16) ? wsum[lane] : 0;
            #pragma unroll
            for (int off = 1; off < 16; off <<= 1) {
                int t = __shfl_up(y, off, 64);
                if (lane >= off) y += t;
            }
            if (lane < 16) wsum[lane] = y;
        }
        __syncthreads();
        int woff  = (wid > 0) ? wsum[wid - 1] : 0;
        int incl  = x + woff;
        int total = wsum[15];
        if (i < n) {
            int ex = carry + incl - v;
            rp[i] = ex;
            cursor[i] = ex;
        }
        carry += total;
        __syncthreads();  // protect wsum before next chunk overwrites
    }
    if (tid == 0) rp[n] = carry;
}

__global__ void k_fill(const int* __restrict__ srcI, const int* __restrict__ dstI,
                       int* __restrict__ cursor, int* __restrict__ colA, int E) {
    int e = blockIdx.x * blockDim.x + threadIdx.x;
    if (e < E) {
        int d = dstI[e];
        int p = atomicAdd(&cursor[d], 1);
        colA[p] = srcI[e];
    }
}

// ---------------- repack row-major [N][128] -> seg-major [8][N][16] ----------------
// blockIdx.y = segment; writes fully coalesced.
__global__ void k_repack(const float* __restrict__ X, float* __restrict__ XS, int n) {
    int i = blockIdx.x * blockDim.x + threadIdx.x;  // float4 idx within segment
    if (i >= n * 4) return;
    int seg  = blockIdx.y;
    int node = i >> 2, c4i = i & 3;
    float4 v = ((const float4*)X)[(size_t)node * 32 + seg * 4 + c4i];
    ((float4*)XS)[(size_t)seg * n * 4 + i] = v;
}

// ---------------- segmented mean aggregation, XCD-pinned, 4 nodes/wave ----------------
// seg = blockIdx.x & 7: consecutive blocks round-robin across 8 XCDs -> XCD k
// keeps only slice k (3.2 MB) L2-resident (R7: FETCH 128->36 MB confirmed).
// R8 accounting: ~640 cyc/wave, ~186 instrs/wave for 16 edges of work ->
// per-wave FIXED cost dominates. Amortize: one wave = 4 CONSECUTIVE node-
// segments; rp[n0..n0+4] = one int4 + scalar (broadcast), prologue paid once.
// Lane = 16 edge slots x 4 float4 channels (16 floats/segment).
__global__ __launch_bounds__(256)
void k_agg_seg(const float* __restrict__ XS, const int* __restrict__ rp,
               const int* __restrict__ colA, float* __restrict__ out, int n) {
    int b = blockIdx.x;
    int seg = b & 7;
    int wave = (b >> 3) * 4 + (threadIdx.x >> 6);
    int n0 = wave * 4;
    if (n0 >= n) return;
    int lane = threadIdx.x & 63;
    int es  = lane >> 2;     // 16 edge slots
    int ch4 = lane & 3;      // 4 float4 channels
    const float4* __restrict__ XS4 = (const float4*)XS;  // [8][n][4]
    size_t segbase4 = (size_t)seg * n * 4;

    // row pointers for 4 consecutive nodes: 5 contiguous ints
    int4 rv = *(const int4*)(rp + n0);
    int  r4 = rp[n0 + 4];
    int begv[5] = {rv.x, rv.y, rv.z, rv.w, r4};

    #pragma unroll
    for (int j = 0; j < 4; ++j) {
        int node = n0 + j;
        if (node >= n) break;
        int beg = begv[j], end = begv[j + 1];
        float4 s = make_float4(0.f, 0.f, 0.f, 0.f);
        int e = beg + es;
        for (; e + 16 < end; e += 32) {   // 2 independent gathers in flight
            int c0 = colA[e];
            int c1 = colA[e + 16];
            float4 v0 = XS4[segbase4 + (size_t)c0 * 4 + ch4];
            float4 v1 = XS4[segbase4 + (size_t)c1 * 4 + ch4];
            s.x += v0.x + v1.x; s.y += v0.y + v1.y;
            s.z += v0.z + v1.z; s.w += v0.w + v1.w;
        }
        if (e < end) {
            int c0 = colA[e];
            float4 v0 = XS4[segbase4 + (size_t)c0 * 4 + ch4];
            s.x += v0.x; s.y += v0.y; s.z += v0.z; s.w += v0.w;
        }
        #pragma unroll
        for (int off = 4; off <= 32; off <<= 1) {
            s.x += __shfl_xor(s.x, off);
            s.y += __shfl_xor(s.y, off);
            s.z += __shfl_xor(s.z, off);
            s.w += __shfl_xor(s.w, off);
        }
        if (es == 0) {
            float inv = 1.f / (float)((end > beg) ? (end - beg) : 1);
            ((float4*)out)[(size_t)node * 32 + seg * 4 + ch4] =
                make_float4(s.x * inv, s.y * inv, s.z * inv, s.w * inv);
        }
    }
}

// ---------------- fallback row-major aggregation (proven R5 path) ----------------
__global__ __launch_bounds__(256)
void k_agg_row(const float* __restrict__ X, const int* __restrict__ rp,
               const int* __restrict__ colA, float* __restrict__ out, int n) {
    int node = (blockIdx.x << 2) + (threadIdx.x >> 6);
    if (node >= n) return;
    int lane = threadIdx.x & 63;
    int eh = lane >> 5;
    int c4 = lane & 31;
    int beg = rp[node], end = rp[node + 1];
    const float4* __restrict__ X4 = (const float4*)X;
    float4 s = make_float4(0.f, 0.f, 0.f, 0.f);
    int e = beg + eh;
    for (; e + 2 < end; e += 4) {
        int c0 = colA[e];
        int c1 = colA[e + 2];
        float4 v0 = X4[(size_t)c0 * 32 + c4];
        float4 v1 = X4[(size_t)c1 * 32 + c4];
        s.x += v0.x + v1.x; s.y += v0.y + v1.y;
        s.z += v0.z + v1.z; s.w += v0.w + v1.w;
    }
    if (e < end) {
        int c0 = colA[e];
        float4 v0 = X4[(size_t)c0 * 32 + c4];
        s.x += v0.x; s.y += v0.y; s.z += v0.z; s.w += v0.w;
    }
    s.x += __shfl_xor(s.x, 32);
    s.y += __shfl_xor(s.y, 32);
    s.z += __shfl_xor(s.z, 32);
    s.w += __shfl_xor(s.w, 32);
    if (eh == 0) {
        float inv = 1.f / (float)((end > beg) ? (end - beg) : 1);
        ((float4*)out)[(size_t)node * 32 + c4] =
            make_float4(s.x * inv, s.y * inv, s.z * inv, s.w * inv);
    }
}

// ---------------- fused SAGE linear, A-tile + W in LDS (R7, frozen) ----------------
template <int MODE, int SEGOUT>
__global__ __launch_bounds__(256, 2)
void k_gemm(const float* __restrict__ A0, const float* __restrict__ A1,
            const float* __restrict__ Wa0, const float* __restrict__ Wb0,
            const float* __restrict__ Wa1, const float* __restrict__ Wb1,
            const float* __restrict__ ba, const float* __restrict__ bb,
            float* __restrict__ out0, float* __restrict__ out1,
            float* __restrict__ outseg, int N) {
    __shared__ float Alds[64 * 132];  // 33.8 KiB, +4 pad
    __shared__ float Wlds[32 * 128];  // 16 KiB
    const int tid = threadIdx.x;
    const int cg  = tid & 15;
    const int rg  = tid >> 4;
    const int rbase = blockIdx.x * 64 + rg * 4;

    float acc[4][8];
    #pragma unroll
    for (int r = 0; r < 4; r++)
        #pragma unroll
        for (int c = 0; c < 8; c++) acc[r][c] = 0.f;

    for (int phase = 0; phase < 2; ++phase) {
        const float* __restrict__ A = phase ? A1 : A0;
        __syncthreads();  // previous phase's Alds reads done
        for (int j = tid; j < 2048; j += 256) {
            int row = j >> 5, c4 = j & 31;
            int grow = blockIdx.x * 64 + row;
            float4 v = (grow < N)
                ? *(const float4*)(A + (size_t)grow * 128 + c4 * 4)
                : make_float4(0.f, 0.f, 0.f, 0.f);
            *(float4*)(Alds + row * 132 + c4 * 4) = v;
        }
        for (int kc = 0; kc < 4; ++kc) {
            __syncthreads();  // covers Alds writes (kc=0) and prior Wlds reads
            if (MODE == 0) {
                const float* __restrict__ W = phase ? Wa1 : Wa0;  // [128][128]
                for (int i = tid; i < 1024; i += 256) {
                    int kr = i >> 5, c4 = i & 31;
                    ((float4*)Wlds)[i] =
                        *(const float4*)(W + (size_t)(kc * 32 + kr) * 128 + c4 * 4);
                }
            } else {
                const float* __restrict__ WA = phase ? Wa1 : Wa0;  // [128][64] mu
                const float* __restrict__ WB = phase ? Wb1 : Wb0;  // [128][64] ls
                for (int i = tid; i < 1024; i += 256) {
                    int kr = i >> 5, c4 = i & 31;
                    const float* s = (c4 < 16)
                        ? (WA + (size_t)(kc * 32 + kr) * 64 + c4 * 4)
                        : (WB + (size_t)(kc * 32 + kr) * 64 + (c4 - 16) * 4);
                    ((float4*)Wlds)[i] = *(const float4*)s;
                }
            }
            __syncthreads();
            #pragma unroll 2
            for (int k = 0; k < 32; k += 4) {
                float4 a[4];
                #pragma unroll
                for (int r = 0; r < 4; r++)
                    a[r] = *(const float4*)(Alds + (rg * 4 + r) * 132 + kc * 32 + k);
                #pragma unroll
                for (int kk = 0; kk < 4; kk++) {
                    float4 w0 = *(const float4*)(Wlds + (k + kk) * 128 + cg * 4);
                    float4 w1 = *(const float4*)(Wlds + (k + kk) * 128 + 64 + cg * 4);
                    #pragma unroll
                    for (int r = 0; r < 4; r++) {
                        float av = (kk == 0) ? a[r].x : (kk == 1) ? a[r].y
                                 : (kk == 2) ? a[r].z : a[r].w;
                        acc[r][0] += av * w0.x;
                        acc[r][1] += av * w0.y;
                        acc[r][2] += av * w0.z;
                        acc[r][3] += av * w0.w;
                        acc[r][4] += av * w1.x;
                        acc[r][5] += av * w1.y;
                        acc[r][6] += av * w1.z;
                        acc[r][7] += av * w1.w;
                    }
                }
            }
        }
    }

    // epilogue
    if (MODE == 0) {
        const float4 bv0 = *(const float4*)(ba + cg * 4);
        const float4 bv1 = *(const float4*)(ba + 64 + cg * 4);
        #pragma unroll
        for (int r = 0; r < 4; r++) {
            int row = rbase + r;
            if (row >= N) continue;
            float4 v0, v1;
            v0.x = fmaxf(acc[r][0] + bv0.x, 0.f);
            v0.y = fmaxf(acc[r][1] + bv0.y, 0.f);
            v0.z = fmaxf(acc[r][2] + bv0.z, 0.f);
            v0.w = fmaxf(acc[r][3] + bv0.w, 0.f);
            v1.x = fmaxf(acc[r][4] + bv1.x, 0.f);
            v1.y = fmaxf(acc[r][5] + bv1.y, 0.f);
            v1.z = fmaxf(acc[r][6] + bv1.z, 0.f);
            v1.w = fmaxf(acc[r][7] + bv1.w, 0.f);
            *(float4*)(out0 + (size_t)row * 128 + cg * 4) = v0;
            *(float4*)(out0 + (size_t)row * 128 + 64 + cg * 4) = v1;
            if (SEGOUT) {
                *(float4*)(outseg + (size_t)(cg >> 2) * N * 16
                           + (size_t)row * 16 + (cg & 3) * 4) = v0;
                *(float4*)(outseg + (size_t)(4 + (cg >> 2)) * N * 16
                           + (size_t)row * 16 + (cg & 3) * 4) = v1;
            }
        }
    } else {
        const float4 bm = *(const float4*)(ba + cg * 4);
        const float4 bl = *(const float4*)(bb + cg * 4);
        #pragma unroll
        for (int r = 0; r < 4; r++) {
            int row = rbase + r;
            if (row >= N) continue;
            float4 vm, vl;
            vm.x = acc[r][0] + bm.x; vm.y = acc[r][1] + bm.y;
            vm.z = acc[r][2] + bm.z; vm.w = acc[r][3] + bm.w;
            vl.x = acc[r][4] + bl.x; vl.y = acc[r][5] + bl.y;
            vl.z = acc[r][6] + bl.z; vl.w = acc[r][7] + bl.w;
            *(float4*)(out0 + (size_t)row * 64 + cg * 4) = vm;
            *(float4*)(out1 + (size_t)row * 64 + cg * 4) = vl;
        }
    }
}

// ---------------- launch ----------------

extern "C" void kernel_launch(void* const* d_in, const int* in_sizes, int n_in,
                              void* d_out, int out_size, void* d_ws, size_t ws_size,
                              hipStream_t stream) {
    const float* x     = (const float*)d_in[0];
    const int*   ei    = (const int*)d_in[1];
    const float* W1_l  = (const float*)d_in[2];
    const float* b1    = (const float*)d_in[3];
    const float* W1_r  = (const float*)d_in[4];
    const float* Wmu_l = (const float*)d_in[5];
    const float* bmu   = (const float*)d_in[6];
    const float* Wmu_r = (const float*)d_in[7];
    const float* Wls_l = (const float*)d_in[8];
    const float* bls   = (const float*)d_in[9];
    const float* Wls_r = (const float*)d_in[10];

    const int N = in_sizes[0] / NODES_CH;  // 50000
    const int E = in_sizes[1] / 2;         // 800000
    const int* srcI = ei;
    const int* dstI = ei + E;

    const int NP = (N + 63) & ~63;
    const int EP = (E + 15) & ~15;

    char* w = (char*)d_ws;
    int* deg    = (int*)w;  w += (size_t)NP * 4;
    int* rp     = (int*)w;  w += (size_t)(NP + 64) * 4;
    int* cursor = (int*)w;  w += (size_t)NP * 4;
    int* colA   = (int*)w;  w += (size_t)EP * 4;
    float* meanb = (float*)w;  w += (size_t)N * 128 * 4;
    float* h     = (float*)w;  w += (size_t)N * 128 * 4;
    float* segb  = (float*)w;  w += (size_t)N * 128 * 4;  // xs, then hs (reuse)

    const bool use_seg =
        ((size_t)((char*)(segb + (size_t)N * 128) - (char*)d_ws)) <= ws_size;

    float* out_mu = (float*)d_out;
    float* out_ls = out_mu + (size_t)N * OUTW;

    // CSR build
    k_zero<<<(N + 255) / 256, 256, 0, stream>>>(deg, N);
    k_degree<<<(E + 255) / 256, 256, 0, stream>>>(dstI, deg, E);
    k_scan<<<1, 1024, 0, stream>>>(deg, rp, cursor, N);
    k_fill<<<(E + 255) / 256, 256, 0, stream>>>(srcI, dstI, cursor, colA, E);

    const int gblocks = (N + 63) / 64;

    if (use_seg) {
        // agg grid: waves-per-seg = ceil(N/4 nodes), 4 waves/block, x8 segs
        const int wps = (N + 3) / 4;
        const int aseg_blocks = ((wps + 3) / 4) * 8;
        // layer 1
        k_repack<<<dim3((N * 4 + 255) / 256, 8), 256, 0, stream>>>(x, segb, N);
        k_agg_seg<<<aseg_blocks, 256, 0, stream>>>(segb, rp, colA, meanb, N);
        k_gemm<0, 1><<<gblocks, 256, 0, stream>>>(
            meanb, x, W1_l, nullptr, W1_r, nullptr, b1, nullptr,
            h, nullptr, segb, N);  // segb becomes hs
        // layer 2
        k_agg_seg<<<aseg_blocks, 256, 0, stream>>>(segb, rp, colA, meanb, N);
        k_gemm<1, 0><<<gblocks, 256, 0, stream>>>(
            meanb, h, Wmu_l, Wls_l, Wmu_r, Wls_r, bmu, bls,
            out_mu, out_ls, nullptr, N);
    } else {
        // fallback: proven row-major gather path
        const int ablocks = (N + 3) / 4;
        k_agg_row<<<ablocks, 256, 0, stream>>>(x, rp, colA, meanb, N);
        k_gemm<0, 0><<<gblocks, 256, 0, stream>>>(
            meanb, x, W1_l, nullptr, W1_r, nullptr, b1, nullptr,
            h, nullptr, nullptr, N);
        k_agg_row<<<ablocks, 256, 0, stream>>>(h, rp, colA, meanb, N);
        k_gemm<1, 0><<<gblocks, 256, 0, stream>>>(
            meanb, h, Wmu_l, Wls_l, Wmu_r, Wls_r, bmu, bls,
            out_mu, out_ls, nullptr, N);
    }
}

// Round 11
// 514.657 us; speedup vs baseline: 1.2505x; 1.0241x over previous
//
#include <hip/hip_runtime.h>

#define NODES_CH 128   // IN_CH == HID == 128
#define OUTW 64

// ---------------- CSR build ----------------

__global__ void k_zero(int* __restrict__ p, int n) {
    int i = blockIdx.x * blockDim.x + threadIdx.x;
    if (i < n) p[i] = 0;
}

__global__ void k_degree(const int* __restrict__ dstI, int* __restrict__ deg, int E) {
    int e = blockIdx.x * blockDim.x + threadIdx.x;
    if (e < E) atomicAdd(&deg[dstI[e]], 1);
}

// single-block exclusive scan; also inits cursor
__global__ __launch_bounds__(1024)
void k_scan(const int* __restrict__ deg, int* __restrict__ rp,
            int* __restrict__ cursor, int n) {
    __shared__ int wsum[16];
    int tid  = threadIdx.x;
    int lane = tid & 63;
    int wid  = tid >> 6;
    int carry = 0;
    for (int base = 0; base < n; base += 1024) {
        int i = base + tid;
        int v = (i < n) ? deg[i] : 0;
        int x = v;
        #pragma unroll
        for (int off = 1; off < 64; off <<= 1) {
            int t = __shfl_up(x, off, 64);
            if (lane >= off) x += t;
        }
        if (lane == 63) wsum[wid] = x;
        __syncthreads();
        if (wid == 0) {
            int y = (lane < 16) ? wsum[lane] : 0;
            #pragma unroll
            for (int off = 1; off < 16; off <<= 1) {
                int t = __shfl_up(y, off, 64);
                if (lane >= off) y += t;
            }
            if (lane < 16) wsum[lane] = y;
        }
        __syncthreads();
        int woff  = (wid > 0) ? wsum[wid - 1] : 0;
        int incl  = x + woff;
        int total = wsum[15];
        if (i < n) {
            int ex = carry + incl - v;
            rp[i] = ex;
            cursor[i] = ex;
        }
        carry += total;
        __syncthreads();  // protect wsum before next chunk overwrites
    }
    if (tid == 0) rp[n] = carry;
}

__global__ void k_fill(const int* __restrict__ srcI, const int* __restrict__ dstI,
                       int* __restrict__ cursor, int* __restrict__ colA, int E) {
    int e = blockIdx.x * blockDim.x + threadIdx.x;
    if (e < E) {
        int d = dstI[e];
        int p = atomicAdd(&cursor[d], 1);
        colA[p] = srcI[e];
    }
}

// ---------------- repack row-major [N][128] -> seg-major [8][N][16] ----------------
// blockIdx.y = segment; writes fully coalesced.
__global__ void k_repack(const float* __restrict__ X, float* __restrict__ XS, int n) {
    int i = blockIdx.x * blockDim.x + threadIdx.x;  // float4 idx within segment
    if (i >= n * 4) return;
    int seg  = blockIdx.y;
    int node = i >> 2, c4i = i & 3;
    float4 v = ((const float4*)X)[(size_t)node * 32 + seg * 4 + c4i];
    ((float4*)XS)[(size_t)seg * n * 4 + i] = v;
}

// ---------------- segmented mean aggregation, XCD-pinned, 4 nodes/wave ----------------
// seg = blockIdx.x & 7: consecutive blocks round-robin across 8 XCDs -> XCD k
// keeps only slice k (3.2 MB) L2-resident (R7: FETCH 128->36 MB confirmed).
// R9: VGPR=20 revealed the unrolled j-loop compiled to 4 SEQUENTIAL dependent
// chains (colA ~200cy -> gather ~200cy -> reduce, x4 ~ 2150 cy/wave measured).
// Now straight-line: issue ALL 8 colA loads (rounds 1+2, addresses known
// upfront), then all gathers, then 4 independent reductions -> chains overlap,
// critical path ~1 round-trip. Residual loop only for deg>32 (P~1e-4).
__global__ __launch_bounds__(256)
void k_agg_seg(const float* __restrict__ XS, const int* __restrict__ rp,
               const int* __restrict__ colA, float* __restrict__ out, int n) {
    int b = blockIdx.x;
    int seg = b & 7;
    int wave = (b >> 3) * 4 + (threadIdx.x >> 6);
    int n0 = wave * 4;
    if (n0 >= n) return;
    int lane = threadIdx.x & 63;
    int es  = lane >> 2;     // 16 edge slots
    int ch4 = lane & 3;      // 4 float4 channels
    const float4* __restrict__ XS4 = (const float4*)XS;  // [8][n][4]
    size_t segb4 = (size_t)seg * n * 4;

    if (n0 + 4 <= n) {  // hot path (always, for n % 4 == 0)
        int4 rv = *(const int4*)(rp + n0);
        int  r4 = rp[n0 + 4];
        const int b0 = rv.x, b1 = rv.y, b2 = rv.z, b3 = rv.w;
        const int E0 = rv.y, E1 = rv.z, E2 = rv.w, E3 = r4;
        const int e0 = b0 + es, e1 = b1 + es, e2 = b2 + es, e3 = b3 + es;
        const int f0 = e0 + 16, f1 = e1 + 16, f2 = e2 + 16, f3 = e3 + 16;

        // batch all index loads (independent; vmcnt-batched)
        int c0 = 0, c1 = 0, c2 = 0, c3 = 0, d0 = 0, d1 = 0, d2 = 0, d3 = 0;
        if (e0 < E0) c0 = colA[e0];
        if (e1 < E1) c1 = colA[e1];
        if (e2 < E2) c2 = colA[e2];
        if (e3 < E3) c3 = colA[e3];
        if (f0 < E0) d0 = colA[f0];
        if (f1 < E1) d1 = colA[f1];
        if (f2 < E2) d2 = colA[f2];
        if (f3 < E3) d3 = colA[f3];

        float4 s0 = make_float4(0.f, 0.f, 0.f, 0.f), s1 = s0, s2 = s0, s3 = s0;
        float4 g;
        // batch gathers (each depends only on its own index)
        if (e0 < E0) { g = XS4[segb4 + (size_t)c0 * 4 + ch4];
                       s0.x += g.x; s0.y += g.y; s0.z += g.z; s0.w += g.w; }
        if (e1 < E1) { g = XS4[segb4 + (size_t)c1 * 4 + ch4];
                       s1.x += g.x; s1.y += g.y; s1.z += g.z; s1.w += g.w; }
        if (e2 < E2) { g = XS4[segb4 + (size_t)c2 * 4 + ch4];
                       s2.x += g.x; s2.y += g.y; s2.z += g.z; s2.w += g.w; }
        if (e3 < E3) { g = XS4[segb4 + (size_t)c3 * 4 + ch4];
                       s3.x += g.x; s3.y += g.y; s3.z += g.z; s3.w += g.w; }
        if (f0 < E0) { g = XS4[segb4 + (size_t)d0 * 4 + ch4];
                       s0.x += g.x; s0.y += g.y; s0.z += g.z; s0.w += g.w; }
        if (f1 < E1) { g = XS4[segb4 + (size_t)d1 * 4 + ch4];
                       s1.x += g.x; s1.y += g.y; s1.z += g.z; s1.w += g.w; }
        if (f2 < E2) { g = XS4[segb4 + (size_t)d2 * 4 + ch4];
                       s2.x += g.x; s2.y += g.y; s2.z += g.z; s2.w += g.w; }
        if (f3 < E3) { g = XS4[segb4 + (size_t)d3 * 4 + ch4];
                       s3.x += g.x; s3.y += g.y; s3.z += g.z; s3.w += g.w; }

        // residual rounds, deg > 32 (Poisson-16: essentially never)
        for (int e = b0 + es + 32; e < E0; e += 16) {
            int c = colA[e]; g = XS4[segb4 + (size_t)c * 4 + ch4];
            s0.x += g.x; s0.y += g.y; s0.z += g.z; s0.w += g.w;
        }
        for (int e = b1 + es + 32; e < E1; e += 16) {
            int c = colA[e]; g = XS4[segb4 + (size_t)c * 4 + ch4];
            s1.x += g.x; s1.y += g.y; s1.z += g.z; s1.w += g.w;
        }
        for (int e = b2 + es + 32; e < E2; e += 16) {
            int c = colA[e]; g = XS4[segb4 + (size_t)c * 4 + ch4];
            s2.x += g.x; s2.y += g.y; s2.z += g.z; s2.w += g.w;
        }
        for (int e = b3 + es + 32; e < E3; e += 16) {
            int c = colA[e]; g = XS4[segb4 + (size_t)c * 4 + ch4];
            s3.x += g.x; s3.y += g.y; s3.z += g.z; s3.w += g.w;
        }

        // 4 independent 16-slot reductions
        #pragma unroll
        for (int off = 4; off <= 32; off <<= 1) {
            s0.x += __shfl_xor(s0.x, off); s0.y += __shfl_xor(s0.y, off);
            s0.z += __shfl_xor(s0.z, off); s0.w += __shfl_xor(s0.w, off);
            s1.x += __shfl_xor(s1.x, off); s1.y += __shfl_xor(s1.y, off);
            s1.z += __shfl_xor(s1.z, off); s1.w += __shfl_xor(s1.w, off);
            s2.x += __shfl_xor(s2.x, off); s2.y += __shfl_xor(s2.y, off);
            s2.z += __shfl_xor(s2.z, off); s2.w += __shfl_xor(s2.w, off);
            s3.x += __shfl_xor(s3.x, off); s3.y += __shfl_xor(s3.y, off);
            s3.z += __shfl_xor(s3.z, off); s3.w += __shfl_xor(s3.w, off);
        }
        if (es == 0) {
            float i0 = 1.f / (float)((E0 > b0) ? (E0 - b0) : 1);
            float i1 = 1.f / (float)((E1 > b1) ? (E1 - b1) : 1);
            float i2 = 1.f / (float)((E2 > b2) ? (E2 - b2) : 1);
            float i3 = 1.f / (float)((E3 > b3) ? (E3 - b3) : 1);
            ((float4*)out)[(size_t)(n0 + 0) * 32 + seg * 4 + ch4] =
                make_float4(s0.x * i0, s0.y * i0, s0.z * i0, s0.w * i0);
            ((float4*)out)[(size_t)(n0 + 1) * 32 + seg * 4 + ch4] =
                make_float4(s1.x * i1, s1.y * i1, s1.z * i1, s1.w * i1);
            ((float4*)out)[(size_t)(n0 + 2) * 32 + seg * 4 + ch4] =
                make_float4(s2.x * i2, s2.y * i2, s2.z * i2, s2.w * i2);
            ((float4*)out)[(size_t)(n0 + 3) * 32 + seg * 4 + ch4] =
                make_float4(s3.x * i3, s3.y * i3, s3.z * i3, s3.w * i3);
        }
    } else {
        // tail wave (n % 4 != 0 only): guarded per-node path
        for (int j = 0; j < 4; ++j) {
            int node = n0 + j;
            if (node >= n) break;
            int beg = rp[node], end = rp[node + 1];
            float4 s = make_float4(0.f, 0.f, 0.f, 0.f);
            for (int e = beg + es; e < end; e += 16) {
                int c = colA[e];
                float4 g = XS4[segb4 + (size_t)c * 4 + ch4];
                s.x += g.x; s.y += g.y; s.z += g.z; s.w += g.w;
            }
            #pragma unroll
            for (int off = 4; off <= 32; off <<= 1) {
                s.x += __shfl_xor(s.x, off); s.y += __shfl_xor(s.y, off);
                s.z += __shfl_xor(s.z, off); s.w += __shfl_xor(s.w, off);
            }
            if (es == 0) {
                float inv = 1.f / (float)((end > beg) ? (end - beg) : 1);
                ((float4*)out)[(size_t)node * 32 + seg * 4 + ch4] =
                    make_float4(s.x * inv, s.y * inv, s.z * inv, s.w * inv);
            }
        }
    }
}

// ---------------- fallback row-major aggregation (proven R5 path) ----------------
__global__ __launch_bounds__(256)
void k_agg_row(const float* __restrict__ X, const int* __restrict__ rp,
               const int* __restrict__ colA, float* __restrict__ out, int n) {
    int node = (blockIdx.x << 2) + (threadIdx.x >> 6);
    if (node >= n) return;
    int lane = threadIdx.x & 63;
    int eh = lane >> 5;
    int c4 = lane & 31;
    int beg = rp[node], end = rp[node + 1];
    const float4* __restrict__ X4 = (const float4*)X;
    float4 s = make_float4(0.f, 0.f, 0.f, 0.f);
    int e = beg + eh;
    for (; e + 2 < end; e += 4) {
        int c0 = colA[e];
        int c1 = colA[e + 2];
        float4 v0 = X4[(size_t)c0 * 32 + c4];
        float4 v1 = X4[(size_t)c1 * 32 + c4];
        s.x += v0.x + v1.x; s.y += v0.y + v1.y;
        s.z += v0.z + v1.z; s.w += v0.w + v1.w;
    }
    if (e < end) {
        int c0 = colA[e];
        float4 v0 = X4[(size_t)c0 * 32 + c4];
        s.x += v0.x; s.y += v0.y; s.z += v0.z; s.w += v0.w;
    }
    s.x += __shfl_xor(s.x, 32);
    s.y += __shfl_xor(s.y, 32);
    s.z += __shfl_xor(s.z, 32);
    s.w += __shfl_xor(s.w, 32);
    if (eh == 0) {
        float inv = 1.f / (float)((end > beg) ? (end - beg) : 1);
        ((float4*)out)[(size_t)node * 32 + c4] =
            make_float4(s.x * inv, s.y * inv, s.z * inv, s.w * inv);
    }
}

// ---------------- fused SAGE linear, A-tile + W in LDS (R7, frozen) ----------------
template <int MODE, int SEGOUT>
__global__ __launch_bounds__(256, 2)
void k_gemm(const float* __restrict__ A0, const float* __restrict__ A1,
            const float* __restrict__ Wa0, const float* __restrict__ Wb0,
            const float* __restrict__ Wa1, const float* __restrict__ Wb1,
            const float* __restrict__ ba, const float* __restrict__ bb,
            float* __restrict__ out0, float* __restrict__ out1,
            float* __restrict__ outseg, int N) {
    __shared__ float Alds[64 * 132];  // 33.8 KiB, +4 pad
    __shared__ float Wlds[32 * 128];  // 16 KiB
    const int tid = threadIdx.x;
    const int cg  = tid & 15;
    const int rg  = tid >> 4;
    const int rbase = blockIdx.x * 64 + rg * 4;

    float acc[4][8];
    #pragma unroll
    for (int r = 0; r < 4; r++)
        #pragma unroll
        for (int c = 0; c < 8; c++) acc[r][c] = 0.f;

    for (int phase = 0; phase < 2; ++phase) {
        const float* __restrict__ A = phase ? A1 : A0;
        __syncthreads();  // previous phase's Alds reads done
        for (int j = tid; j < 2048; j += 256) {
            int row = j >> 5, c4 = j & 31;
            int grow = blockIdx.x * 64 + row;
            float4 v = (grow < N)
                ? *(const float4*)(A + (size_t)grow * 128 + c4 * 4)
                : make_float4(0.f, 0.f, 0.f, 0.f);
            *(float4*)(Alds + row * 132 + c4 * 4) = v;
        }
        for (int kc = 0; kc < 4; ++kc) {
            __syncthreads();  // covers Alds writes (kc=0) and prior Wlds reads
            if (MODE == 0) {
                const float* __restrict__ W = phase ? Wa1 : Wa0;  // [128][128]
                for (int i = tid; i < 1024; i += 256) {
                    int kr = i >> 5, c4 = i & 31;
                    ((float4*)Wlds)[i] =
                        *(const float4*)(W + (size_t)(kc * 32 + kr) * 128 + c4 * 4);
                }
            } else {
                const float* __restrict__ WA = phase ? Wa1 : Wa0;  // [128][64] mu
                const float* __restrict__ WB = phase ? Wb1 : Wb0;  // [128][64] ls
                for (int i = tid; i < 1024; i += 256) {
                    int kr = i >> 5, c4 = i & 31;
                    const float* s = (c4 < 16)
                        ? (WA + (size_t)(kc * 32 + kr) * 64 + c4 * 4)
                        : (WB + (size_t)(kc * 32 + kr) * 64 + (c4 - 16) * 4);
                    ((float4*)Wlds)[i] = *(const float4*)s;
                }
            }
            __syncthreads();
            #pragma unroll 2
            for (int k = 0; k < 32; k += 4) {
                float4 a[4];
                #pragma unroll
                for (int r = 0; r < 4; r++)
                    a[r] = *(const float4*)(Alds + (rg * 4 + r) * 132 + kc * 32 + k);
                #pragma unroll
                for (int kk = 0; kk < 4; kk++) {
                    float4 w0 = *(const float4*)(Wlds + (k + kk) * 128 + cg * 4);
                    float4 w1 = *(const float4*)(Wlds + (k + kk) * 128 + 64 + cg * 4);
                    #pragma unroll
                    for (int r = 0; r < 4; r++) {
                        float av = (kk == 0) ? a[r].x : (kk == 1) ? a[r].y
                                 : (kk == 2) ? a[r].z : a[r].w;
                        acc[r][0] += av * w0.x;
                        acc[r][1] += av * w0.y;
                        acc[r][2] += av * w0.z;
                        acc[r][3] += av * w0.w;
                        acc[r][4] += av * w1.x;
                        acc[r][5] += av * w1.y;
                        acc[r][6] += av * w1.z;
                        acc[r][7] += av * w1.w;
                    }
                }
            }
        }
    }

    // epilogue
    if (MODE == 0) {
        const float4 bv0 = *(const float4*)(ba + cg * 4);
        const float4 bv1 = *(const float4*)(ba + 64 + cg * 4);
        #pragma unroll
        for (int r = 0; r < 4; r++) {
            int row = rbase + r;
            if (row >= N) continue;
            float4 v0, v1;
            v0.x = fmaxf(acc[r][0] + bv0.x, 0.f);
            v0.y = fmaxf(acc[r][1] + bv0.y, 0.f);
            v0.z = fmaxf(acc[r][2] + bv0.z, 0.f);
            v0.w = fmaxf(acc[r][3] + bv0.w, 0.f);
            v1.x = fmaxf(acc[r][4] + bv1.x, 0.f);
            v1.y = fmaxf(acc[r][5] + bv1.y, 0.f);
            v1.z = fmaxf(acc[r][6] + bv1.z, 0.f);
            v1.w = fmaxf(acc[r][7] + bv1.w, 0.f);
            *(float4*)(out0 + (size_t)row * 128 + cg * 4) = v0;
            *(float4*)(out0 + (size_t)row * 128 + 64 + cg * 4) = v1;
            if (SEGOUT) {
                *(float4*)(outseg + (size_t)(cg >> 2) * N * 16
                           + (size_t)row * 16 + (cg & 3) * 4) = v0;
                *(float4*)(outseg + (size_t)(4 + (cg >> 2)) * N * 16
                           + (size_t)row * 16 + (cg & 3) * 4) = v1;
            }
        }
    } else {
        const float4 bm = *(const float4*)(ba + cg * 4);
        const float4 bl = *(const float4*)(bb + cg * 4);
        #pragma unroll
        for (int r = 0; r < 4; r++) {
            int row = rbase + r;
            if (row >= N) continue;
            float4 vm, vl;
            vm.x = acc[r][0] + bm.x; vm.y = acc[r][1] + bm.y;
            vm.z = acc[r][2] + bm.z; vm.w = acc[r][3] + bm.w;
            vl.x = acc[r][4] + bl.x; vl.y = acc[r][5] + bl.y;
            vl.z = acc[r][6] + bl.z; vl.w = acc[r][7] + bl.w;
            *(float4*)(out0 + (size_t)row * 64 + cg * 4) = vm;
            *(float4*)(out1 + (size_t)row * 64 + cg * 4) = vl;
        }
    }
}

// ---------------- launch ----------------

extern "C" void kernel_launch(void* const* d_in, const int* in_sizes, int n_in,
                              void* d_out, int out_size, void* d_ws, size_t ws_size,
                              hipStream_t stream) {
    const float* x     = (const float*)d_in[0];
    const int*   ei    = (const int*)d_in[1];
    const float* W1_l  = (const float*)d_in[2];
    const float* b1    = (const float*)d_in[3];
    const float* W1_r  = (const float*)d_in[4];
    const float* Wmu_l = (const float*)d_in[5];
    const float* bmu   = (const float*)d_in[6];
    const float* Wmu_r = (const float*)d_in[7];
    const float* Wls_l = (const float*)d_in[8];
    const float* bls   = (const float*)d_in[9];
    const float* Wls_r = (const float*)d_in[10];

    const int N = in_sizes[0] / NODES_CH;  // 50000
    const int E = in_sizes[1] / 2;         // 800000
    const int* srcI = ei;
    const int* dstI = ei + E;

    const int NP = (N + 63) & ~63;
    const int EP = (E + 15) & ~15;

    char* w = (char*)d_ws;
    int* deg    = (int*)w;  w += (size_t)NP * 4;
    int* rp     = (int*)w;  w += (size_t)(NP + 64) * 4;
    int* cursor = (int*)w;  w += (size_t)NP * 4;
    int* colA   = (int*)w;  w += (size_t)EP * 4;
    float* meanb = (float*)w;  w += (size_t)N * 128 * 4;
    float* h     = (float*)w;  w += (size_t)N * 128 * 4;
    float* segb  = (float*)w;  w += (size_t)N * 128 * 4;  // xs, then hs (reuse)

    const bool use_seg =
        ((size_t)((char*)(segb + (size_t)N * 128) - (char*)d_ws)) <= ws_size;

    float* out_mu = (float*)d_out;
    float* out_ls = out_mu + (size_t)N * OUTW;

    // CSR build
    k_zero<<<(N + 255) / 256, 256, 0, stream>>>(deg, N);
    k_degree<<<(E + 255) / 256, 256, 0, stream>>>(dstI, deg, E);
    k_scan<<<1, 1024, 0, stream>>>(deg, rp, cursor, N);
    k_fill<<<(E + 255) / 256, 256, 0, stream>>>(srcI, dstI, cursor, colA, E);

    const int gblocks = (N + 63) / 64;

    if (use_seg) {
        // agg grid: waves-per-seg = ceil(N/4 nodes), 4 waves/block, x8 segs
        const int wps = (N + 3) / 4;
        const int aseg_blocks = ((wps + 3) / 4) * 8;
        // layer 1
        k_repack<<<dim3((N * 4 + 255) / 256, 8), 256, 0, stream>>>(x, segb, N);
        k_agg_seg<<<aseg_blocks, 256, 0, stream>>>(segb, rp, colA, meanb, N);
        k_gemm<0, 1><<<gblocks, 256, 0, stream>>>(
            meanb, x, W1_l, nullptr, W1_r, nullptr, b1, nullptr,
            h, nullptr, segb, N);  // segb becomes hs
        // layer 2
        k_agg_seg<<<aseg_blocks, 256, 0, stream>>>(segb, rp, colA, meanb, N);
        k_gemm<1, 0><<<gblocks, 256, 0, stream>>>(
            meanb, h, Wmu_l, Wls_l, Wmu_r, Wls_r, bmu, bls,
            out_mu, out_ls, nullptr, N);
    } else {
        // fallback: proven row-major gather path
        const int ablocks = (N + 3) / 4;
        k_agg_row<<<ablocks, 256, 0, stream>>>(x, rp, colA, meanb, N);
        k_gemm<0, 0><<<gblocks, 256, 0, stream>>>(
            meanb, x, W1_l, nullptr, W1_r, nullptr, b1, nullptr,
            h, nullptr, nullptr, N);
        k_agg_row<<<ablocks, 256, 0, stream>>>(h, rp, colA, meanb, N);
        k_gemm<1, 0><<<gblocks, 256, 0, stream>>>(
            meanb, h, Wmu_l, Wls_l, Wmu_r, Wls_r, bmu, bls,
            out_mu, out_ls, nullptr, N);
    }
}

// Round 12
// 494.697 us; speedup vs baseline: 1.3010x; 1.0403x over previous
//
#include <hip/hip_runtime.h>

#define NODES_CH 128   // IN_CH == HID == 128
#define OUTW 64

// ---------------- CSR build ----------------

__global__ void k_zero(int* __restrict__ p, int n) {
    int i = blockIdx.x * blockDim.x + threadIdx.x;
    if (i < n) p[i] = 0;
}

__global__ void k_degree(const int* __restrict__ dstI, int* __restrict__ deg, int E) {
    int e = blockIdx.x * blockDim.x + threadIdx.x;
    if (e < E) atomicAdd(&deg[dstI[e]], 1);
}

// single-block exclusive scan; also inits cursor
__global__ __launch_bounds__(1024)
void k_scan(const int* __restrict__ deg, int* __restrict__ rp,
            int* __restrict__ cursor, int n) {
    __shared__ int wsum[16];
    int tid  = threadIdx.x;
    int lane = tid & 63;
    int wid  = tid >> 6;
    int carry = 0;
    for (int base = 0; base < n; base += 1024) {
        int i = base + tid;
        int v = (i < n) ? deg[i] : 0;
        int x = v;
        #pragma unroll
        for (int off = 1; off < 64; off <<= 1) {
            int t = __shfl_up(x, off, 64);
            if (lane >= off) x += t;
        }
        if (lane == 63) wsum[wid] = x;
        __syncthreads();
        if (wid == 0) {
            int y = (lane < 16) ? wsum[lane] : 0;
            #pragma unroll
            for (int off = 1; off < 16; off <<= 1) {
                int t = __shfl_up(y, off, 64);
                if (lane >= off) y += t;
            }
            if (lane < 16) wsum[lane] = y;
        }
        __syncthreads();
        int woff  = (wid > 0) ? wsum[wid - 1] : 0;
        int incl  = x + woff;
        int total = wsum[15];
        if (i < n) {
            int ex = carry + incl - v;
            rp[i] = ex;
            cursor[i] = ex;
        }
        carry += total;
        __syncthreads();  // protect wsum before next chunk overwrites
    }
    if (tid == 0) rp[n] = carry;
}

__global__ void k_fill(const int* __restrict__ srcI, const int* __restrict__ dstI,
                       int* __restrict__ cursor, int* __restrict__ colA, int E) {
    int e = blockIdx.x * blockDim.x + threadIdx.x;
    if (e < E) {
        int d = dstI[e];
        int p = atomicAdd(&cursor[d], 1);
        colA[p] = srcI[e];
    }
}

// ---------------- repack row-major [N][128] -> seg-major [8][N][16] ----------------
// blockIdx.y = segment; writes fully coalesced.
__global__ void k_repack(const float* __restrict__ X, float* __restrict__ XS, int n) {
    int i = blockIdx.x * blockDim.x + threadIdx.x;  // float4 idx within segment
    if (i >= n * 4) return;
    int seg  = blockIdx.y;
    int node = i >> 2, c4i = i & 3;
    float4 v = ((const float4*)X)[(size_t)node * 32 + seg * 4 + c4i];
    ((float4*)XS)[(size_t)seg * n * 4 + i] = v;
}

// ---------------- segmented mean aggregation, XCD-pinned, 4 nodes/wave ----------------
// seg = blockIdx.x & 7 -> XCD-pinned slices (R7: FETCH 128->36 MB confirmed).
// R11: VGPR=24 exposed the real serializer — a SINGLE reused float4 `g` for
// all 8 gathers forced waitcnt-per-load. Now: 8 DISTINCT index regs + 8
// DISTINCT gather regs, loads UNCONDITIONAL at clamped addresses (colA entry
// is always a valid node id), validity applied as 0/1 multiplier via fma.
// No branches in the hot path -> all 8 colA loads then all 8 gathers issue
// back-to-back; critical path ~1 colA trip + 1 gather trip + reduce.
__global__ __launch_bounds__(256)
void k_agg_seg(const float* __restrict__ XS, const int* __restrict__ rp,
               const int* __restrict__ colA, float* __restrict__ out,
               int n, int Etot) {
    int b = blockIdx.x;
    int seg = b & 7;
    int wave = (b >> 3) * 4 + (threadIdx.x >> 6);
    int n0 = wave * 4;
    if (n0 >= n) return;
    int lane = threadIdx.x & 63;
    int es  = lane >> 2;     // 16 edge slots
    int ch4 = lane & 3;      // 4 float4 channels
    const float4* __restrict__ XS4 = (const float4*)XS;  // [8][n][4]
    size_t segb4 = (size_t)seg * n * 4;

    if (n0 + 4 <= n) {  // hot path (always, for n % 4 == 0)
        int4 rv = *(const int4*)(rp + n0);
        int  r4 = rp[n0 + 4];
        const int b0 = rv.x, b1 = rv.y, b2 = rv.z, b3 = rv.w;
        const int E0 = rv.y, E1 = rv.z, E2 = rv.w, E3 = r4;
        const int e0 = b0 + es, e1 = b1 + es, e2 = b2 + es, e3 = b3 + es;
        const int f0 = e0 + 16, f1 = e1 + 16, f2 = e2 + 16, f3 = e3 + 16;
        const int Em1 = Etot - 1;

        // 8 unconditional colA loads, clamped, DISTINCT registers
        int c0 = colA[min(e0, Em1)];
        int c1 = colA[min(e1, Em1)];
        int c2 = colA[min(e2, Em1)];
        int c3 = colA[min(e3, Em1)];
        int d0 = colA[min(f0, Em1)];
        int d1 = colA[min(f1, Em1)];
        int d2 = colA[min(f2, Em1)];
        int d3 = colA[min(f3, Em1)];

        // 8 unconditional gathers, DISTINCT registers (indices always valid ids)
        float4 g0 = XS4[segb4 + (size_t)c0 * 4 + ch4];
        float4 g1 = XS4[segb4 + (size_t)c1 * 4 + ch4];
        float4 g2 = XS4[segb4 + (size_t)c2 * 4 + ch4];
        float4 g3 = XS4[segb4 + (size_t)c3 * 4 + ch4];
        float4 h0 = XS4[segb4 + (size_t)d0 * 4 + ch4];
        float4 h1 = XS4[segb4 + (size_t)d1 * 4 + ch4];
        float4 h2 = XS4[segb4 + (size_t)d2 * 4 + ch4];
        float4 h3 = XS4[segb4 + (size_t)d3 * 4 + ch4];

        // validity as 0/1 multipliers -> fma, no branches
        const float k0 = (e0 < E0) ? 1.f : 0.f;
        const float k1 = (e1 < E1) ? 1.f : 0.f;
        const float k2 = (e2 < E2) ? 1.f : 0.f;
        const float k3 = (e3 < E3) ? 1.f : 0.f;
        const float m0 = (f0 < E0) ? 1.f : 0.f;
        const float m1 = (f1 < E1) ? 1.f : 0.f;
        const float m2 = (f2 < E2) ? 1.f : 0.f;
        const float m3 = (f3 < E3) ? 1.f : 0.f;

        float4 s0, s1, s2, s3;
        s0.x = k0 * g0.x + m0 * h0.x; s0.y = k0 * g0.y + m0 * h0.y;
        s0.z = k0 * g0.z + m0 * h0.z; s0.w = k0 * g0.w + m0 * h0.w;
        s1.x = k1 * g1.x + m1 * h1.x; s1.y = k1 * g1.y + m1 * h1.y;
        s1.z = k1 * g1.z + m1 * h1.z; s1.w = k1 * g1.w + m1 * h1.w;
        s2.x = k2 * g2.x + m2 * h2.x; s2.y = k2 * g2.y + m2 * h2.y;
        s2.z = k2 * g2.z + m2 * h2.z; s2.w = k2 * g2.w + m2 * h2.w;
        s3.x = k3 * g3.x + m3 * h3.x; s3.y = k3 * g3.y + m3 * h3.y;
        s3.z = k3 * g3.z + m3 * h3.z; s3.w = k3 * g3.w + m3 * h3.w;

        // residual rounds, deg > 32 (Poisson-16: essentially never taken)
        for (int e = b0 + es + 32; e < E0; e += 16) {
            int c = colA[e]; float4 g = XS4[segb4 + (size_t)c * 4 + ch4];
            s0.x += g.x; s0.y += g.y; s0.z += g.z; s0.w += g.w;
        }
        for (int e = b1 + es + 32; e < E1; e += 16) {
            int c = colA[e]; float4 g = XS4[segb4 + (size_t)c * 4 + ch4];
            s1.x += g.x; s1.y += g.y; s1.z += g.z; s1.w += g.w;
        }
        for (int e = b2 + es + 32; e < E2; e += 16) {
            int c = colA[e]; float4 g = XS4[segb4 + (size_t)c * 4 + ch4];
            s2.x += g.x; s2.y += g.y; s2.z += g.z; s2.w += g.w;
        }
        for (int e = b3 + es + 32; e < E3; e += 16) {
            int c = colA[e]; float4 g = XS4[segb4 + (size_t)c * 4 + ch4];
            s3.x += g.x; s3.y += g.y; s3.z += g.z; s3.w += g.w;
        }

        // 4 independent 16-slot reductions
        #pragma unroll
        for (int off = 4; off <= 32; off <<= 1) {
            s0.x += __shfl_xor(s0.x, off); s0.y += __shfl_xor(s0.y, off);
            s0.z += __shfl_xor(s0.z, off); s0.w += __shfl_xor(s0.w, off);
            s1.x += __shfl_xor(s1.x, off); s1.y += __shfl_xor(s1.y, off);
            s1.z += __shfl_xor(s1.z, off); s1.w += __shfl_xor(s1.w, off);
            s2.x += __shfl_xor(s2.x, off); s2.y += __shfl_xor(s2.y, off);
            s2.z += __shfl_xor(s2.z, off); s2.w += __shfl_xor(s2.w, off);
            s3.x += __shfl_xor(s3.x, off); s3.y += __shfl_xor(s3.y, off);
            s3.z += __shfl_xor(s3.z, off); s3.w += __shfl_xor(s3.w, off);
        }
        if (es == 0) {
            float i0 = 1.f / (float)((E0 > b0) ? (E0 - b0) : 1);
            float i1 = 1.f / (float)((E1 > b1) ? (E1 - b1) : 1);
            float i2 = 1.f / (float)((E2 > b2) ? (E2 - b2) : 1);
            float i3 = 1.f / (float)((E3 > b3) ? (E3 - b3) : 1);
            ((float4*)out)[(size_t)(n0 + 0) * 32 + seg * 4 + ch4] =
                make_float4(s0.x * i0, s0.y * i0, s0.z * i0, s0.w * i0);
            ((float4*)out)[(size_t)(n0 + 1) * 32 + seg * 4 + ch4] =
                make_float4(s1.x * i1, s1.y * i1, s1.z * i1, s1.w * i1);
            ((float4*)out)[(size_t)(n0 + 2) * 32 + seg * 4 + ch4] =
                make_float4(s2.x * i2, s2.y * i2, s2.z * i2, s2.w * i2);
            ((float4*)out)[(size_t)(n0 + 3) * 32 + seg * 4 + ch4] =
                make_float4(s3.x * i3, s3.y * i3, s3.z * i3, s3.w * i3);
        }
    } else {
        // tail wave (n % 4 != 0 only): guarded per-node path
        for (int j = 0; j < 4; ++j) {
            int node = n0 + j;
            if (node >= n) break;
            int beg = rp[node], end = rp[node + 1];
            float4 s = make_float4(0.f, 0.f, 0.f, 0.f);
            for (int e = beg + es; e < end; e += 16) {
                int c = colA[e];
                float4 g = XS4[segb4 + (size_t)c * 4 + ch4];
                s.x += g.x; s.y += g.y; s.z += g.z; s.w += g.w;
            }
            #pragma unroll
            for (int off = 4; off <= 32; off <<= 1) {
                s.x += __shfl_xor(s.x, off); s.y += __shfl_xor(s.y, off);
                s.z += __shfl_xor(s.z, off); s.w += __shfl_xor(s.w, off);
            }
            if (es == 0) {
                float inv = 1.f / (float)((end > beg) ? (end - beg) : 1);
                ((float4*)out)[(size_t)node * 32 + seg * 4 + ch4] =
                    make_float4(s.x * inv, s.y * inv, s.z * inv, s.w * inv);
            }
        }
    }
}

// ---------------- fallback row-major aggregation (proven R5 path) ----------------
__global__ __launch_bounds__(256)
void k_agg_row(const float* __restrict__ X, const int* __restrict__ rp,
               const int* __restrict__ colA, float* __restrict__ out, int n) {
    int node = (blockIdx.x << 2) + (threadIdx.x >> 6);
    if (node >= n) return;
    int lane = threadIdx.x & 63;
    int eh = lane >> 5;
    int c4 = lane & 31;
    int beg = rp[node], end = rp[node + 1];
    const float4* __restrict__ X4 = (const float4*)X;
    float4 s = make_float4(0.f, 0.f, 0.f, 0.f);
    int e = beg + eh;
    for (; e + 2 < end; e += 4) {
        int c0 = colA[e];
        int c1 = colA[e + 2];
        float4 v0 = X4[(size_t)c0 * 32 + c4];
        float4 v1 = X4[(size_t)c1 * 32 + c4];
        s.x += v0.x + v1.x; s.y += v0.y + v1.y;
        s.z += v0.z + v1.z; s.w += v0.w + v1.w;
    }
    if (e < end) {
        int c0 = colA[e];
        float4 v0 = X4[(size_t)c0 * 32 + c4];
        s.x += v0.x; s.y += v0.y; s.z += v0.z; s.w += v0.w;
    }
    s.x += __shfl_xor(s.x, 32);
    s.y += __shfl_xor(s.y, 32);
    s.z += __shfl_xor(s.z, 32);
    s.w += __shfl_xor(s.w, 32);
    if (eh == 0) {
        float inv = 1.f / (float)((end > beg) ? (end - beg) : 1);
        ((float4*)out)[(size_t)node * 32 + c4] =
            make_float4(s.x * inv, s.y * inv, s.z * inv, s.w * inv);
    }
}

// ---------------- fused SAGE linear, A-tile + W in LDS (R7, frozen) ----------------
template <int MODE, int SEGOUT>
__global__ __launch_bounds__(256, 2)
void k_gemm(const float* __restrict__ A0, const float* __restrict__ A1,
            const float* __restrict__ Wa0, const float* __restrict__ Wb0,
            const float* __restrict__ Wa1, const float* __restrict__ Wb1,
            const float* __restrict__ ba, const float* __restrict__ bb,
            float* __restrict__ out0, float* __restrict__ out1,
            float* __restrict__ outseg, int N) {
    __shared__ float Alds[64 * 132];  // 33.8 KiB, +4 pad
    __shared__ float Wlds[32 * 128];  // 16 KiB
    const int tid = threadIdx.x;
    const int cg  = tid & 15;
    const int rg  = tid >> 4;
    const int rbase = blockIdx.x * 64 + rg * 4;

    float acc[4][8];
    #pragma unroll
    for (int r = 0; r < 4; r++)
        #pragma unroll
        for (int c = 0; c < 8; c++) acc[r][c] = 0.f;

    for (int phase = 0; phase < 2; ++phase) {
        const float* __restrict__ A = phase ? A1 : A0;
        __syncthreads();  // previous phase's Alds reads done
        for (int j = tid; j < 2048; j += 256) {
            int row = j >> 5, c4 = j & 31;
            int grow = blockIdx.x * 64 + row;
            float4 v = (grow < N)
                ? *(const float4*)(A + (size_t)grow * 128 + c4 * 4)
                : make_float4(0.f, 0.f, 0.f, 0.f);
            *(float4*)(Alds + row * 132 + c4 * 4) = v;
        }
        for (int kc = 0; kc < 4; ++kc) {
            __syncthreads();  // covers Alds writes (kc=0) and prior Wlds reads
            if (MODE == 0) {
                const float* __restrict__ W = phase ? Wa1 : Wa0;  // [128][128]
                for (int i = tid; i < 1024; i += 256) {
                    int kr = i >> 5, c4 = i & 31;
                    ((float4*)Wlds)[i] =
                        *(const float4*)(W + (size_t)(kc * 32 + kr) * 128 + c4 * 4);
                }
            } else {
                const float* __restrict__ WA = phase ? Wa1 : Wa0;  // [128][64] mu
                const float* __restrict__ WB = phase ? Wb1 : Wb0;  // [128][64] ls
                for (int i = tid; i < 1024; i += 256) {
                    int kr = i >> 5, c4 = i & 31;
                    const float* s = (c4 < 16)
                        ? (WA + (size_t)(kc * 32 + kr) * 64 + c4 * 4)
                        : (WB + (size_t)(kc * 32 + kr) * 64 + (c4 - 16) * 4);
                    ((float4*)Wlds)[i] = *(const float4*)s;
                }
            }
            __syncthreads();
            #pragma unroll 2
            for (int k = 0; k < 32; k += 4) {
                float4 a[4];
                #pragma unroll
                for (int r = 0; r < 4; r++)
                    a[r] = *(const float4*)(Alds + (rg * 4 + r) * 132 + kc * 32 + k);
                #pragma unroll
                for (int kk = 0; kk < 4; kk++) {
                    float4 w0 = *(const float4*)(Wlds + (k + kk) * 128 + cg * 4);
                    float4 w1 = *(const float4*)(Wlds + (k + kk) * 128 + 64 + cg * 4);
                    #pragma unroll
                    for (int r = 0; r < 4; r++) {
                        float av = (kk == 0) ? a[r].x : (kk == 1) ? a[r].y
                                 : (kk == 2) ? a[r].z : a[r].w;
                        acc[r][0] += av * w0.x;
                        acc[r][1] += av * w0.y;
                        acc[r][2] += av * w0.z;
                        acc[r][3] += av * w0.w;
                        acc[r][4] += av * w1.x;
                        acc[r][5] += av * w1.y;
                        acc[r][6] += av * w1.z;
                        acc[r][7] += av * w1.w;
                    }
                }
            }
        }
    }

    // epilogue
    if (MODE == 0) {
        const float4 bv0 = *(const float4*)(ba + cg * 4);
        const float4 bv1 = *(const float4*)(ba + 64 + cg * 4);
        #pragma unroll
        for (int r = 0; r < 4; r++) {
            int row = rbase + r;
            if (row >= N) continue;
            float4 v0, v1;
            v0.x = fmaxf(acc[r][0] + bv0.x, 0.f);
            v0.y = fmaxf(acc[r][1] + bv0.y, 0.f);
            v0.z = fmaxf(acc[r][2] + bv0.z, 0.f);
            v0.w = fmaxf(acc[r][3] + bv0.w, 0.f);
            v1.x = fmaxf(acc[r][4] + bv1.x, 0.f);
            v1.y = fmaxf(acc[r][5] + bv1.y, 0.f);
            v1.z = fmaxf(acc[r][6] + bv1.z, 0.f);
            v1.w = fmaxf(acc[r][7] + bv1.w, 0.f);
            *(float4*)(out0 + (size_t)row * 128 + cg * 4) = v0;
            *(float4*)(out0 + (size_t)row * 128 + 64 + cg * 4) = v1;
            if (SEGOUT) {
                *(float4*)(outseg + (size_t)(cg >> 2) * N * 16
                           + (size_t)row * 16 + (cg & 3) * 4) = v0;
                *(float4*)(outseg + (size_t)(4 + (cg >> 2)) * N * 16
                           + (size_t)row * 16 + (cg & 3) * 4) = v1;
            }
        }
    } else {
        const float4 bm = *(const float4*)(ba + cg * 4);
        const float4 bl = *(const float4*)(bb + cg * 4);
        #pragma unroll
        for (int r = 0; r < 4; r++) {
            int row = rbase + r;
            if (row >= N) continue;
            float4 vm, vl;
            vm.x = acc[r][0] + bm.x; vm.y = acc[r][1] + bm.y;
            vm.z = acc[r][2] + bm.z; vm.w = acc[r][3] + bm.w;
            vl.x = acc[r][4] + bl.x; vl.y = acc[r][5] + bl.y;
            vl.z = acc[r][6] + bl.z; vl.w = acc[r][7] + bl.w;
            *(float4*)(out0 + (size_t)row * 64 + cg * 4) = vm;
            *(float4*)(out1 + (size_t)row * 64 + cg * 4) = vl;
        }
    }
}

// ---------------- launch ----------------

extern "C" void kernel_launch(void* const* d_in, const int* in_sizes, int n_in,
                              void* d_out, int out_size, void* d_ws, size_t ws_size,
                              hipStream_t stream) {
    const float* x     = (const float*)d_in[0];
    const int*   ei    = (const int*)d_in[1];
    const float* W1_l  = (const float*)d_in[2];
    const float* b1    = (const float*)d_in[3];
    const float* W1_r  = (const float*)d_in[4];
    const float* Wmu_l = (const float*)d_in[5];
    const float* bmu   = (const float*)d_in[6];
    const float* Wmu_r = (const float*)d_in[7];
    const float* Wls_l = (const float*)d_in[8];
    const float* bls   = (const float*)d_in[9];
    const float* Wls_r = (const float*)d_in[10];

    const int N = in_sizes[0] / NODES_CH;  // 50000
    const int E = in_sizes[1] / 2;         // 800000
    const int* srcI = ei;
    const int* dstI = ei + E;

    const int NP = (N + 63) & ~63;
    const int EP = (E + 15) & ~15;

    char* w = (char*)d_ws;
    int* deg    = (int*)w;  w += (size_t)NP * 4;
    int* rp     = (int*)w;  w += (size_t)(NP + 64) * 4;
    int* cursor = (int*)w;  w += (size_t)NP * 4;
    int* colA   = (int*)w;  w += (size_t)EP * 4;
    float* meanb = (float*)w;  w += (size_t)N * 128 * 4;
    float* h     = (float*)w;  w += (size_t)N * 128 * 4;
    float* segb  = (float*)w;  w += (size_t)N * 128 * 4;  // xs, then hs (reuse)

    const bool use_seg =
        ((size_t)((char*)(segb + (size_t)N * 128) - (char*)d_ws)) <= ws_size;

    float* out_mu = (float*)d_out;
    float* out_ls = out_mu + (size_t)N * OUTW;

    // CSR build
    k_zero<<<(N + 255) / 256, 256, 0, stream>>>(deg, N);
    k_degree<<<(E + 255) / 256, 256, 0, stream>>>(dstI, deg, E);
    k_scan<<<1, 1024, 0, stream>>>(deg, rp, cursor, N);
    k_fill<<<(E + 255) / 256, 256, 0, stream>>>(srcI, dstI, cursor, colA, E);

    const int gblocks = (N + 63) / 64;

    if (use_seg) {
        // agg grid: waves-per-seg = ceil(N/4 nodes), 4 waves/block, x8 segs
        const int wps = (N + 3) / 4;
        const int aseg_blocks = ((wps + 3) / 4) * 8;
        // layer 1
        k_repack<<<dim3((N * 4 + 255) / 256, 8), 256, 0, stream>>>(x, segb, N);
        k_agg_seg<<<aseg_blocks, 256, 0, stream>>>(segb, rp, colA, meanb, N, E);
        k_gemm<0, 1><<<gblocks, 256, 0, stream>>>(
            meanb, x, W1_l, nullptr, W1_r, nullptr, b1, nullptr,
            h, nullptr, segb, N);  // segb becomes hs
        // layer 2
        k_agg_seg<<<aseg_blocks, 256, 0, stream>>>(segb, rp, colA, meanb, N, E);
        k_gemm<1, 0><<<gblocks, 256, 0, stream>>>(
            meanb, h, Wmu_l, Wls_l, Wmu_r, Wls_r, bmu, bls,
            out_mu, out_ls, nullptr, N);
    } else {
        // fallback: proven row-major gather path
        const int ablocks = (N + 3) / 4;
        k_agg_row<<<ablocks, 256, 0, stream>>>(x, rp, colA, meanb, N);
        k_gemm<0, 0><<<gblocks, 256, 0, stream>>>(
            meanb, x, W1_l, nullptr, W1_r, nullptr, b1, nullptr,
            h, nullptr, nullptr, N);
        k_agg_row<<<ablocks, 256, 0, stream>>>(h, rp, colA, meanb, N);
        k_gemm<1, 0><<<gblocks, 256, 0, stream>>>(
            meanb, h, Wmu_l, Wls_l, Wmu_r, Wls_r, bmu, bls,
            out_mu, out_ls, nullptr, N);
    }
}